// Round 4
// baseline (1018.669 us; speedup 1.0000x reference)
//
#include <hip/hip_runtime.h>

// ---------------------------------------------------------------------------
// AdaLanczosNet forward, faithful f32 re-implementation of the JAX reference.
// B=16, N=256, NUM_ATOM=64, K=20, HIDDEN=(128,128), SCALES=10.
// Round 4: fix round-3 VGPR spill in lanczos via __launch_bounds__(1024,4)
// (block = 16 waves = 4/SIMD -> VGPR cap 512, Lreg[64] stays in registers).
// Merge beta/qnorm reductions to cut barriers.
// ---------------------------------------------------------------------------

constexpr int nB = 16;
constexpr int nN = 256;
constexpr int nK = 20;
constexpr float EPSF = 1.1920928955078125e-07f;  // np.finfo(float32).eps
constexpr float LBF  = 1e-4f;                    // lanczos breakdown tol

#define DEV static __device__ __forceinline__

// ---------------- Threefry-2x32 (20 rounds) --------------------------------
DEV void tf2x32(unsigned k0, unsigned k1, unsigned x0, unsigned x1,
                unsigned &o0, unsigned &o1) {
  unsigned ks2 = k0 ^ k1 ^ 0x1BD11BDAu;
#define RND(r) { x0 += x1; x1 = (x1 << r) | (x1 >> (32 - r)); x1 ^= x0; }
  x0 += k0;  x1 += k1;
  RND(13) RND(15) RND(26) RND(6)
  x0 += k1;  x1 += ks2 + 1u;
  RND(17) RND(29) RND(16) RND(24)
  x0 += ks2; x1 += k0 + 2u;
  RND(13) RND(15) RND(26) RND(6)
  x0 += k0;  x1 += k1 + 3u;
  RND(17) RND(29) RND(16) RND(24)
  x0 += k1;  x1 += ks2 + 4u;
  RND(13) RND(15) RND(26) RND(6)
  x0 += ks2; x1 += k0 + 5u;
#undef RND
  o0 = x0; o1 = x1;
}

// XLA ErfInv (f32, Giles polynomial, w = -log1p(-x^2))
DEV float erfinv_f32(float x) {
  float w = -log1pf(-x * x);
  float p;
  if (w < 5.0f) {
    w -= 2.5f;
    p = 2.81022636e-08f;
    p = fmaf(p, w, 3.43273939e-07f);
    p = fmaf(p, w, -3.5233877e-06f);
    p = fmaf(p, w, -4.39150654e-06f);
    p = fmaf(p, w, 0.00021858087f);
    p = fmaf(p, w, -0.00125372503f);
    p = fmaf(p, w, -0.00417768164f);
    p = fmaf(p, w, 0.246640727f);
    p = fmaf(p, w, 1.50140941f);
  } else {
    w = sqrtf(w) - 3.0f;
    p = -0.000200214257f;
    p = fmaf(p, w, 0.000100950558f);
    p = fmaf(p, w, 0.00134934322f);
    p = fmaf(p, w, -0.00367342844f);
    p = fmaf(p, w, 0.00573950773f);
    p = fmaf(p, w, -0.0076224613f);
    p = fmaf(p, w, 0.00943887047f);
    p = fmaf(p, w, 1.00167406f);
    p = fmaf(p, w, 2.83297682f);
  }
  return p * x;
}

DEV float jax_normal(unsigned k0, unsigned k1, unsigned idx) {
  unsigned o0, o1;
  tf2x32(k0, k1, 0u /*hi*/, idx /*lo*/, o0, o1);
  unsigned bits = o0 ^ o1;
  float u = __uint_as_float((bits >> 9) | 0x3f800000u) - 1.0f;  // [0,1)
  const float lo = -0.99999994f;
  float v = fmaxf(lo, u * 2.0f + lo);
  return 1.41421356237309515f * erfinv_f32(v);
}

// ---------------- reductions ----------------------------------------------
DEV double waveRedD(double v) {
#pragma unroll
  for (int m = 32; m > 0; m >>= 1) v += __shfl_xor(v, m, 64);
  return v;
}
DEV float waveRedF(float v) {
#pragma unroll
  for (int m = 32; m > 0; m >>= 1) v += __shfl_xor(v, m, 64);
  return v;
}
DEV double blockSumD(double v, double *s4) {
  v = waveRedD(v);
  int w = threadIdx.x >> 6;
  __syncthreads();
  if ((threadIdx.x & 63) == 0) s4[w] = v;
  __syncthreads();
  return s4[0] + s4[1] + s4[2] + s4[3];
}
// 1024-thread block sum (16 waves)
DEV double blockSum16(double v, double *red16) {
  v = waveRedD(v);
  __syncthreads();
  if ((threadIdx.x & 63) == 0) red16[threadIdx.x >> 6] = v;
  __syncthreads();
  double s = 0.0;
#pragma unroll
  for (int w = 0; w < 16; w++) s += red16[w];
  return s;
}
// dual-value 1024-thread block sum (one barrier pair for two sums)
DEV void blockSum16x2(double va, double vb, double *redA, double *redB,
                      double &oa, double &ob) {
  va = waveRedD(va);
  vb = waveRedD(vb);
  __syncthreads();
  if ((threadIdx.x & 63) == 0) {
    redA[threadIdx.x >> 6] = va;
    redB[threadIdx.x >> 6] = vb;
  }
  __syncthreads();
  double sa = 0.0, sb = 0.0;
#pragma unroll
  for (int w = 0; w < 16; w++) { sa += redA[w]; sb += redB[w]; }
  oa = sa; ob = sb;
}

// ---------------- stage 1: embedding table + one-hot state ----------------
__global__ __launch_bounds__(256) void feat_table_kernel(
    const float *__restrict__ w1, const float *__restrict__ b1,
    const float *__restrict__ w2, const float *__restrict__ b2,
    float *__restrict__ table) {
  int a = blockIdx.x, t = threadIdx.x;
  __shared__ float hh[1024];
  __shared__ float part[256];
  for (int k = t; k < 1024; k += 256)
    hh[k] = fmaxf(w1[(size_t)a * 1024 + k] + b1[k], 0.f);
  __syncthreads();
  int d = t & 63, slice = t >> 6;
  float acc = 0.f;
  for (int k = slice * 256; k < slice * 256 + 256; k++)
    acc += hh[k] * w2[(size_t)k * 64 + d];
  part[t] = acc;
  __syncthreads();
  if (t < 64)
    table[(size_t)a * 64 + t] =
        part[t] + part[64 + t] + part[128 + t] + part[192 + t] + b2[t];
}

__global__ void feat_state_kernel(const int *__restrict__ nf,
                                  const float *__restrict__ table,
                                  float *__restrict__ feat,
                                  float *__restrict__ state0) {
  int g = blockIdx.x, t = threadIdx.x;  // 64 threads
  int a = nf[g];
  feat[(size_t)g * 64 + t] = table[(size_t)a * 64 + t];
  state0[(size_t)g * 64 + t] = (t == a) ? 1.f : 0.f;
}

// featT[b][d][n] = feat[b][n][d]  (LDS-tiled transpose, 64x64 tiles)
__global__ __launch_bounds__(256) void feat_tr_kernel(
    const float *__restrict__ feat, float *__restrict__ featT) {
  int g = blockIdx.x;           // nB*4
  int bb = g >> 2, n0 = (g & 3) * 64;
  int t = threadIdx.x;
  int c = t & 63, r4 = t >> 6;
  __shared__ float tl[64][65];
  for (int r = r4; r < 64; r += 4)
    tl[r][c] = feat[((size_t)(bb * nN + n0 + r)) * 64 + c];
  __syncthreads();
  for (int r = r4; r < 64; r += 4)
    featT[(size_t)bb * 16384 + (size_t)r * nN + n0 + c] = tl[c][r];
}

// ---------------- stage 2: graph laplacian --------------------------------
__global__ __launch_bounds__(256) void dist2_kernel(
    const float *__restrict__ feat, const float *__restrict__ featT,
    float *__restrict__ G, double *__restrict__ part) {
  int g = blockIdx.x;             // nB*64
  int bb = g >> 6, i0 = (g & 63) * 4;
  int t = threadIdx.x;
  __shared__ float fi[4][64];
  __shared__ double s4[4];
  {
    int r = t >> 6, d = t & 63;
    fi[r][d] = feat[((size_t)(bb * nN + i0 + r)) * 64 + d];
  }
  __syncthreads();
  const float *ft = featT + (size_t)bb * 16384 + t;
  float a0 = 0.f, a1 = 0.f, a2 = 0.f, a3 = 0.f;
#pragma unroll 8
  for (int d = 0; d < 64; d++) {
    float x = ft[(size_t)d * nN];
    float d0 = fi[0][d] - x; a0 += d0 * d0;
    float d1 = fi[1][d] - x; a1 += d1 * d1;
    float d2 = fi[2][d] - x; a2 += d2 * d2;
    float d3 = fi[3][d] - x; a3 += d3 * d3;
  }
  size_t base = ((size_t)bb * nN + i0) * nN + t;
  G[base]           = a0;
  G[base + nN]      = a1;
  G[base + 2 * nN]  = a2;
  G[base + 3 * nN]  = a3;
  double tot = blockSumD((double)a0 + (double)a1 + (double)a2 + (double)a3, s4);
  if (t == 0) part[g] = tot;
}

__global__ __launch_bounds__(64) void sigred_kernel(
    const double *__restrict__ part, float *__restrict__ sigma2) {
  int bb = blockIdx.x, t = threadIdx.x;
  double v = part[(size_t)bb * 64 + t];
  v = waveRedD(v);
  if (t == 0) sigma2[bb] = (float)(v / 65536.0);
}

__global__ __launch_bounds__(256) void arow_kernel(
    const float *__restrict__ Lfull, const float *__restrict__ sigma2,
    float *__restrict__ G, float *__restrict__ Dv) {
  int g = blockIdx.x;
  int i = g % nN, bb = g / nN;
  int t = threadIdx.x;
  __shared__ double s4[4];
  float sig = sigma2[bb];
  size_t idx2 = ((size_t)bb * nN + i) * nN + t;
  float a = expf(-G[idx2] / sig) * Lfull[idx2 * 4];  // adj mask = L[...,0]
  G[idx2] = a;
  double rs = blockSumD((double)a, s4);
  if (t == 0) {
    float r = (float)rs;
    float pad = (r == 0.f) ? 1.f : 0.f;
    Dv[(size_t)bb * nN + i] = 1.f / sqrtf(r + pad);
  }
}

// scale G in place AND write GT = Lk^T (tiled transpose)
__global__ __launch_bounds__(256) void lkscale_tr_kernel(
    float *__restrict__ G, const float *__restrict__ Dv,
    float *__restrict__ GT) {
  int g = blockIdx.x;                 // nB*16
  int bb = g >> 4, tile = g & 15;
  int ti = (tile >> 2) * 64, tj = (tile & 3) * 64;
  int t = threadIdx.x;
  int lj = t & 63, li0 = t >> 6;
  __shared__ float tl[64][65];
  for (int r = li0; r < 64; r += 4) {
    int i = ti + r;
    size_t idx = ((size_t)bb * nN + i) * nN + tj + lj;
    float v = Dv[(size_t)bb * nN + i] * G[idx] * Dv[(size_t)bb * nN + tj + lj];
    G[idx] = v;
    tl[r][lj] = v;
  }
  __syncthreads();
  for (int r = li0; r < 64; r += 4) {
    int j = tj + r;
    GT[((size_t)bb * nN + j) * nN + ti + lj] = tl[lj][r];
  }
}

// ---------------- stage 3: Lanczos (1024 threads, matrix in registers) ----
// __launch_bounds__(1024, 4): 16 waves/block = 4 waves/SIMD -> VGPR cap 512;
// without the 2nd arg the compiler capped at 64 VGPRs and spilled Lreg[64]
// to scratch (round-3 regression: WRITE_SIZE 345K -> 4185K).
__global__ __launch_bounds__(1024, 4) void lanczos_kernel(
    const float *__restrict__ GT, float *__restrict__ Qout,
    float *__restrict__ Tout) {
  __shared__ float Qb[nK * nN];          // [k][n]  20 KiB
  __shared__ float qc[nN], qp[nN], zz[nN];
  __shared__ double zpart[4][nN];        // 8 KiB
  __shared__ float qn2[nK], sAl[nK], sBe[nK], sVa[nK], coef[nK];
  __shared__ double red[16], redB[16];
  int bb = blockIdx.x, u = threadIdx.x;
  int t = u & 255, q = u >> 8;           // thread (q,t): rows q*64.. of col t
  int wv = u >> 6, lane = u & 63;

  // preload Lk[t][q*64+jj] = GT[(q*64+jj)*256 + t]  (coalesced, once)
  float Lreg[64];
  const float *Gp = GT + (size_t)bb * (nN * nN) + (size_t)(q * 64) * nN + t;
#pragma unroll
  for (int jj = 0; jj < 64; jj++) Lreg[jj] = Gp[(size_t)jj * nN];

  // q0 = normal(fold_in(key(42),0), (B,N)); q0 /= ||q0||
  unsigned k0, k1;
  tf2x32(0u, 42u, 0u, 0u, k0, k1);
  float val = 0.f;
  if (q == 0) val = jax_normal(k0, k1, (unsigned)(bb * nN + t));
  double n2 = blockSum16((double)val * (double)val, red);
  if (q == 0) {
    qc[t] = val / sqrtf((float)n2);
    qp[t] = 0.f;
  }
  __syncthreads();

  float beta_prev = 0.f, validf = 1.f;

  for (int i = 0; i < nK; i++) {
    // --- z = Lk @ qc : register FMAs, LDS-broadcast qc
    {
      double a0 = 0, a1 = 0, a2 = 0, a3 = 0;
      const float *qv = qc + q * 64;
#pragma unroll
      for (int jj = 0; jj < 64; jj += 4) {
        a0 += (double)Lreg[jj + 0] * (double)qv[jj + 0];
        a1 += (double)Lreg[jj + 1] * (double)qv[jj + 1];
        a2 += (double)Lreg[jj + 2] * (double)qv[jj + 2];
        a3 += (double)Lreg[jj + 3] * (double)qv[jj + 3];
      }
      zpart[q][t] = (a0 + a1) + (a2 + a3);
    }
    __syncthreads();
    float zi = 0.f;
    if (q == 0) {
      double zf = (zpart[0][t] + zpart[1][t]) + (zpart[2][t] + zpart[3][t]);
      zi = (float)zf;
    }
    // alpha
    double ad = blockSum16((q == 0) ? (double)qc[t] * (double)zi : 0.0, red);
    float alpha = (float)ad;
    if (q == 0) {
      zi = zi - alpha * qc[t] - beta_prev * qp[t];
      zz[t] = zi;
    }
    __syncthreads();
    // --- double block reorthogonalization against Q[:, :i], 16-wave parallel
    for (int pass = 0; pass < 2; pass++) {
      for (int k = wv; k < i; k += 16) {
        double p = 0.0;
        for (int n0 = lane; n0 < nN; n0 += 64)
          p += (double)Qb[k * nN + n0] * (double)zz[n0];
        p = waveRedD(p);
        if (lane == 0)
          coef[k] = (float)(p / ((double)qn2[k] + (double)EPSF));
      }
      __syncthreads();
      if (q == 0) {
        double sub = 0.0;
        for (int k = 0; k < i; k++)
          sub += (double)Qb[k * nN + t] * (double)coef[k];
        zz[t] = (float)((double)zz[t] - sub);
      }
      __syncthreads();
    }
    // --- beta and ||qc||^2 in ONE dual reduction (saves a barrier pair)
    float zfin = (q == 0) ? zz[t] : 0.f;
    float qcv  = (q == 0) ? qc[t] : 0.f;
    double b2, q2;
    blockSum16x2((double)zfin * (double)zfin, (double)qcv * (double)qcv,
                 red, redB, b2, q2);
    float beta = sqrtf((float)b2);
    validf *= (beta >= LBF) ? 1.f : 0.f;
    // store column i
    if (q == 0) Qb[i * nN + t] = qc[t];
    if (u == 0) {
      qn2[i] = (float)q2;
      sAl[i] = alpha;
      sBe[i] = beta;
      sVa[i] = validf;
    }
    __syncthreads();
    if (q == 0) {
      float qnext = zz[t] * validf / (beta + EPSF);
      qp[t] = qc[t];
      qc[t] = qnext;
    }
    __syncthreads();
    beta_prev = beta;
  }

  // idx = sum(valid); mask Q rows/cols; build T
  float idxf = 0.f;
  for (int k = 0; k < nK; k++) idxf += sVa[k];
  int idx = (int)idxf;
  if (q == 0) {
    float rowok = ((t < idx) || (idx >= nN)) ? 1.f : 0.f;
    for (int k = 0; k < nK; k++)
      Qout[((size_t)bb * nN + t) * nK + k] = Qb[k * nN + t] * sVa[k] * rowok;
  }
  for (int e = u; e < nK * nK; e += 1024) {
    int i = e / nK, j = e % nK;
    float v = 0.f;
    if (i == j) v = sAl[i] * sVa[i];
    else if (j == i + 1) v = sBe[i] * sVa[i];
    else if (i == j + 1) v = sBe[j] * sVa[j];
    Tout[(size_t)bb * nK * nK + e] = v;
  }
}

// ---------------- stage 4: gated T powers (per batch) ----------------------
__global__ __launch_bounds__(64) void spect_power_kernel(
    const float *__restrict__ Tin, float *__restrict__ Tpow, int fold_data) {
  __shared__ float T_[nK * nK], TT[nK * nK], TTn[nK * nK];
  __shared__ float Tb[nK], Tbn[nK];
  int bb = blockIdx.x, t = threadIdx.x;
  for (int e = t; e < nK * nK; e += 64) {
    float v = Tin[(size_t)bb * nK * nK + e];
    T_[e] = v;
    TT[e] = v;
  }
  unsigned k0, k1;
  tf2x32(0u, 42u, 0u, (unsigned)fold_data, k0, k1);
  if (t < nK) Tb[t] = jax_normal(k0, k1, (unsigned)(bb * nK + t));
  __syncthreads();
  float pv = (t < nK) ? Tb[t] * Tb[t] : 0.f;
  float nb = sqrtf(waveRedF(pv));
  if (t < nK) Tb[t] = Tb[t] / nb;
  __syncthreads();
  for (int ii = 0; ii < 8; ii++) {
    if (ii == 3 || ii == 5 || ii == 7) {
      int s = (ii - 3) / 2;
      for (int e = t; e < nK * nK; e += 64)
        Tpow[((size_t)s * nB + bb) * nK * nK + e] = TT[e];
    }
    __syncthreads();
    for (int e = t; e < nK * nK; e += 64) {
      int i = e / nK, j = e % nK;
      float a = 0.f;
      for (int l = 0; l < nK; l++) a += TT[i * nK + l] * T_[l * nK + j];
      TTn[e] = a;
    }
    if (t < nK) {
      float a = 0.f;
      for (int l = 0; l < nK; l++) a += T_[t * nK + l] * Tb[l];
      Tbn[t] = a;
    }
    __syncthreads();
    float pn = (t < nK) ? Tbn[t] * Tb[t] : 0.f;
    float pd = (t < nK) ? Tb[t] * Tb[t] : 0.f;
    float num = waveRedF(pn);
    float den = waveRedF(pd);
    float lmax = num / (den + EPSF);
    float keep = (fabsf(lmax) <= 1.0f) ? 1.f : 0.f;
    __syncthreads();
    for (int e = t; e < nK * nK; e += 64) TT[e] = TTn[e] * keep;
    float p2 = (t < nK) ? Tbn[t] * Tbn[t] : 0.f;
    float nn = sqrtf(waveRedF(p2));
    if (t < nK) Tb[t] = Tbn[t] / (nn + EPSF);
    __syncthreads();
  }
}

// ---------------- stage 4b: eigen maps ------------------------------------
__global__ __launch_bounds__(256) void eig1_kernel(
    const float *__restrict__ Tpow, const float *__restrict__ w1p,
    const float *__restrict__ b1p, float *__restrict__ h) {
  int g = blockIdx.x;                 // 3*B*4 blocks
  int chunk = g & 3, bb = (g >> 2) % nB, s = g / (4 * nB);
  int t = threadIdx.x;
  __shared__ float tp[nK * nK];
  for (int e = t; e < nK * nK; e += 256)
    tp[e] = Tpow[((size_t)s * nB + bb) * nK * nK + e];
  __syncthreads();
  int o = chunk * 256 + t;
  const float *W = w1p + (size_t)s * 400 * 1024;
  float acc = b1p[(size_t)s * 1024 + o];
  for (int k = 0; k < 400; k++) acc += tp[k] * W[(size_t)k * 1024 + o];
  h[((size_t)s * nB + bb) * 1024 + o] = fmaxf(acc, 0.f);
}

__global__ __launch_bounds__(256) void eig2_kernel(
    const float *__restrict__ h, const float *__restrict__ w2p,
    const float *__restrict__ b2p, float *__restrict__ DD) {
  int g = blockIdx.x;  // 3*B blocks
  int bb = g % nB, s = g / nB;
  int t = threadIdx.x;
  __shared__ float hh[1024];
  __shared__ float raw[nK * nK];
  for (int e = t; e < 1024; e += 256)
    hh[e] = h[((size_t)s * nB + bb) * 1024 + e];
  __syncthreads();
  const float *W = w2p + (size_t)s * 1024 * 400;
  for (int kl = t; kl < 400; kl += 256) {
    float acc = b2p[(size_t)s * 400 + kl];
    for (int o = 0; o < 1024; o++) acc += hh[o] * W[(size_t)o * 400 + kl];
    raw[kl] = acc;
  }
  __syncthreads();
  for (int e = t; e < 400; e += 256) {
    int i = e / nK, j = e % nK;
    int mi = i < j ? i : j, ma = i < j ? j : i;
    DD[((size_t)s * nB + bb) * 400 + e] = raw[mi * nK + ma];
  }
}

// ---------------- stage 5: message assembly -------------------------------
__global__ void qtstate_kernel(const float *__restrict__ Q,
                               const float *__restrict__ state,
                               float *__restrict__ E) {
  int g = blockIdx.x;
  int k = g % nK, bb = g / nK;
  int t = threadIdx.x, Din = blockDim.x;
  __shared__ float qcol[nN];
  for (int n = t; n < nN; n += Din) qcol[n] = Q[((size_t)bb * nN + n) * nK + k];
  __syncthreads();
  const float *st = state + (size_t)bb * nN * Din;
  float acc = 0.f;
  for (int n = 0; n < nN; n++) acc += qcol[n] * st[(size_t)n * Din + t];
  E[((size_t)bb * nK + k) * Din + t] = acc;
}

__global__ void ddE_kernel(const float *__restrict__ DD,
                           const float *__restrict__ E,
                           float *__restrict__ F) {
  int g = blockIdx.x;
  int k = g % nK, bb = (g / nK) % nB, s = g / (nK * nB);
  int t = threadIdx.x, Din = blockDim.x;
  __shared__ float dr[nK];
  if (t < nK) dr[t] = DD[((size_t)s * nB + bb) * 400 + k * nK + t];
  __syncthreads();
  float acc = 0.f;
  for (int l = 0; l < nK; l++)
    acc += dr[l] * E[((size_t)bb * nK + l) * Din + t];
  F[(((size_t)s * nB + bb) * nK + k) * Din + t] = acc;
}

// out = Lk @ in, 8 rows per block (rows staged in LDS, input reused 8x)
__global__ void lk_matvec_kernel(const float *__restrict__ Lk,
                                 const float *__restrict__ in, int inStride,
                                 float *__restrict__ out, int outStride) {
  int g = blockIdx.x;                 // nB*nN/8
  int bb = g >> 5, r0 = (g & 31) * 8;
  int t = threadIdx.x, Din = blockDim.x;
  __shared__ float rows[8][nN];
  for (int e = t; e < 8 * nN; e += Din) {
    int r = e >> 8, j = e & 255;
    rows[r][j] = Lk[((size_t)bb * nN + r0 + r) * nN + j];
  }
  __syncthreads();
  float acc[8] = {0.f, 0.f, 0.f, 0.f, 0.f, 0.f, 0.f, 0.f};
  const float *ip = in + (size_t)bb * nN * inStride + t;
  for (int j = 0; j < nN; j++) {
    float x = ip[(size_t)j * inStride];
#pragma unroll
    for (int r = 0; r < 8; r++) acc[r] += rows[r][j] * x;
  }
#pragma unroll
  for (int r = 0; r < 8; r++)
    out[((size_t)bb * nN + r0 + r) * outStride + t] = acc[r];
}

// msg parts 3..5: Q @ F[s]
__global__ void longmsg_kernel(const float *__restrict__ Q,
                               const float *__restrict__ F,
                               float *__restrict__ msg, int C) {
  int g = blockIdx.x;
  int i = g % nN, bb = g / nN;
  int t = threadIdx.x, Din = blockDim.x;
  __shared__ float qr[nK];
  if (t < nK) qr[t] = Q[((size_t)bb * nN + i) * nK + t];
  __syncthreads();
  for (int s = 0; s < 3; s++) {
    float acc = 0.f;
    for (int k = 0; k < nK; k++)
      acc += qr[k] * F[(((size_t)s * nB + bb) * nK + k) * Din + t];
    msg[((size_t)bb * nN + i) * C + (3 + s) * Din + t] = acc;
  }
}

// msg parts 6..9: L[...,e] @ state, 4 rows/block, float4 over the 4 edgetypes
__global__ void edgemsg_kernel(const float *__restrict__ Lfull,
                               const float *__restrict__ state,
                               float *__restrict__ msg, int C) {
  int g = blockIdx.x;                 // nB*nN/4
  int bb = g >> 6, r0 = (g & 63) * 4;
  int t = threadIdx.x, Din = blockDim.x;
  __shared__ float4 rows4[4][nN];     // 16 KiB
  const float4 *L4 = (const float4 *)Lfull;
  for (int e = t; e < 4 * nN; e += Din) {
    int r = e >> 8, j = e & 255;
    rows4[r][j] = L4[((size_t)bb * nN + r0 + r) * nN + j];
  }
  __syncthreads();
  float acc[4][4];
#pragma unroll
  for (int r = 0; r < 4; r++)
#pragma unroll
    for (int e = 0; e < 4; e++) acc[r][e] = 0.f;
  const float *st = state + (size_t)bb * nN * Din + t;
  for (int j = 0; j < nN; j++) {
    float x = st[(size_t)j * Din];
#pragma unroll
    for (int r = 0; r < 4; r++) {
      float4 lv = rows4[r][j];
      acc[r][0] += lv.x * x;
      acc[r][1] += lv.y * x;
      acc[r][2] += lv.z * x;
      acc[r][3] += lv.w * x;
    }
  }
#pragma unroll
  for (int r = 0; r < 4; r++)
#pragma unroll
    for (int e = 0; e < 4; e++)
      msg[((size_t)bb * nN + r0 + r) * C + (6 + e) * Din + t] = acc[r][e];
}

// state_next = relu(msg @ W + b); 16 rows per block to amortize W reads
__global__ __launch_bounds__(256) void filt_kernel(
    const float *__restrict__ msg, const float *__restrict__ W,
    const float *__restrict__ bias, float *__restrict__ out, int C) {
  int g = blockIdx.x;                 // (B*N)/16
  int base = g * 16;
  int t = threadIdx.x;
  int o = t & 127, ih = t >> 7;       // ih: 0/1 -> rows 0..7 / 8..15
  __shared__ float mt[16][64];
  float acc[8];
  float bo = bias[o];
#pragma unroll
  for (int r = 0; r < 8; r++) acc[r] = bo;
  for (int c0 = 0; c0 < C; c0 += 64) {
    __syncthreads();
    for (int e = t; e < 16 * 64; e += 256) {
      int r = e >> 6, c = e & 63;
      mt[r][c] = msg[((size_t)(base + r)) * C + c0 + c];
    }
    __syncthreads();
    for (int c = 0; c < 64; c++) {
      float w = W[(size_t)(c0 + c) * 128 + o];
#pragma unroll
      for (int r = 0; r < 8; r++) acc[r] += mt[ih * 8 + r][c] * w;
    }
  }
#pragma unroll
  for (int r = 0; r < 8; r++)
    out[((size_t)(base + ih * 8 + r)) * 128 + o] = fmaxf(acc[r], 0.f);
}

// ---------------- stage 6: readout ----------------------------------------
__global__ __launch_bounds__(256) void score_kernel(
    const float *__restrict__ state, const float *__restrict__ wo,
    const float *__restrict__ bo, const float *__restrict__ aw,
    const float *__restrict__ ab, float *__restrict__ out) {
  __shared__ double s4[4];
  int bb = blockIdx.x, t = threadIdx.x;
  const float *st = state + ((size_t)bb * nN + t) * 128;
  float sy = bo[0], sa = ab[0];
  for (int o = 0; o < 128; o++) {
    float v = st[o];
    sy += v * wo[o];
    sa += v * aw[o];
  }
  float att = 1.f / (1.f + expf(-sa));
  double m = blockSumD((double)(att * sy), s4);
  if (t == 0) out[bb] = (float)(m / (double)nN);
}

// ---------------------------------------------------------------------------
extern "C" void kernel_launch(void *const *d_in, const int *in_sizes, int n_in,
                              void *d_out, int out_size, void *d_ws,
                              size_t ws_size, hipStream_t stream) {
  (void)in_sizes; (void)n_in; (void)out_size;
  const int   *node_feat = (const int *)d_in[0];
  const float *Lfull     = (const float *)d_in[1];
  const float *emb_w1    = (const float *)d_in[2];
  const float *emb_b1    = (const float *)d_in[3];
  const float *emb_w2    = (const float *)d_in[4];
  const float *emb_b2    = (const float *)d_in[5];
  const float *eig_w1    = (const float *)d_in[6];
  const float *eig_b1    = (const float *)d_in[7];
  const float *eig_w2    = (const float *)d_in[8];
  const float *eig_b2    = (const float *)d_in[9];
  const float *filt_w0   = (const float *)d_in[10];
  const float *filt_b0   = (const float *)d_in[11];
  const float *filt_w1   = (const float *)d_in[12];
  const float *filt_b1   = (const float *)d_in[13];
  const float *filt_wo   = (const float *)d_in[14];
  const float *filt_bo   = (const float *)d_in[15];
  const float *att_w     = (const float *)d_in[16];
  const float *att_b     = (const float *)d_in[17];

  // workspace layout (floats)
  float *ws   = (float *)d_ws;
  float *G    = ws;                    // B*N*N           = 1048576
  float *msg  = G + 1048576;           // B*N*1280        = 5242880
  float *st0  = msg + 5242880;         // B*N*64
  float *st1  = st0 + 262144;          // B*N*128
  float *st2  = st1 + 524288;          // B*N*128
  float *feat = st2 + 524288;          // B*N*64
  float *table= feat + 262144;         // 64*64
  float *Q    = table + 4096;          // B*N*K
  float *T    = Q + 81920;             // B*K*K
  float *Tpow = T + 6400;              // 3*B*K*K
  float *DD   = Tpow + 19200;          // 3*B*K*K
  float *h    = DD + 19200;            // 3*B*1024
  float *E    = h + 49152;             // B*K*128
  float *F    = E + 40960;             // 3*B*K*128
  float *Dv   = F + 122880;            // B*N
  double *part   = (double *)(Dv + 4096);   // B*N doubles (8-byte aligned)
  float  *sigma2 = (float *)(part + nB * nN);
  // GT and featT alias the msg region (both dead before msg is written)
  float *GT    = msg;                  // B*N*N = 1048576 floats
  float *featT = msg + 1048576;        // B*64*256 = 262144 floats
  const size_t needBytes = (size_t)(8220432) * 4;
  if (ws_size < needBytes) return;

  // embedding + one-hot state
  feat_table_kernel<<<64, 256, 0, stream>>>(emb_w1, emb_b1, emb_w2, emb_b2, table);
  feat_state_kernel<<<nB * nN, 64, 0, stream>>>(node_feat, table, feat, st0);
  feat_tr_kernel<<<nB * 4, 256, 0, stream>>>(feat, featT);
  // laplacian
  dist2_kernel<<<nB * 64, 256, 0, stream>>>(feat, featT, G, part);
  sigred_kernel<<<nB, 64, 0, stream>>>(part, sigma2);
  arow_kernel<<<nB * nN, 256, 0, stream>>>(Lfull, sigma2, G, Dv);
  lkscale_tr_kernel<<<nB * 16, 256, 0, stream>>>(G, Dv, GT);
  // lanczos (matrix slice in registers)
  lanczos_kernel<<<nB, 1024, 0, stream>>>(GT, Q, T);

  const float *stateIn = st0;
  float *stOut[2] = {st1, st2};
  int Din = 64;
  for (int tt = 0; tt < 2; tt++) {
    int C = 10 * Din;
    spect_power_kernel<<<nB, 64, 0, stream>>>(T, Tpow, tt + 1);
    eig1_kernel<<<3 * nB * 4, 256, 0, stream>>>(Tpow, eig_w1, eig_b1, h);
    eig2_kernel<<<3 * nB, 256, 0, stream>>>(h, eig_w2, eig_b2, DD);
    qtstate_kernel<<<nB * nK, Din, 0, stream>>>(Q, stateIn, E);
    ddE_kernel<<<3 * nB * nK, Din, 0, stream>>>(DD, E, F);
    // short diffusion chain -> parts 0..2
    lk_matvec_kernel<<<nB * nN / 8, Din, 0, stream>>>(G, stateIn, Din, msg + 0 * Din, C);
    lk_matvec_kernel<<<nB * nN / 8, Din, 0, stream>>>(G, msg + 0 * Din, C, msg + 1 * Din, C);
    lk_matvec_kernel<<<nB * nN / 8, Din, 0, stream>>>(G, msg + 1 * Din, C, msg + 2 * Din, C);
    // long spectral -> parts 3..5
    longmsg_kernel<<<nB * nN, Din, 0, stream>>>(Q, F, msg, C);
    // edge types -> parts 6..9
    edgemsg_kernel<<<nB * nN / 4, Din, 0, stream>>>(Lfull, stateIn, msg, C);
    // filter layer
    filt_kernel<<<nB * nN / 16, 256, 0, stream>>>(
        msg, tt ? filt_w1 : filt_w0, tt ? filt_b1 : filt_b0, stOut[tt], C);
    stateIn = stOut[tt];
    Din = 128;
  }
  score_kernel<<<nB, 256, 0, stream>>>(st2, filt_wo, filt_bo, att_w, att_b,
                                       (float *)d_out);
}

// Round 5
// 899.456 us; speedup vs baseline: 1.1325x; 1.1325x over previous
//
#include <hip/hip_runtime.h>

// ---------------------------------------------------------------------------
// AdaLanczosNet forward, faithful f32 re-implementation of the JAX reference.
// B=16, N=256, NUM_ATOM=64, K=20, HIDDEN=(128,128), SCALES=10.
// Round 5: lanczos = 256 threads, one matrix ROW per thread in VGPRs.
// amdgpu_waves_per_eu(1,1) FORCES the register budget (launch_bounds' 2nd arg
// is only a floor on occupancy -> r3/r4 spilled to scratch at VGPR_Count=64).
// ---------------------------------------------------------------------------

constexpr int nB = 16;
constexpr int nN = 256;
constexpr int nK = 20;
constexpr float EPSF = 1.1920928955078125e-07f;  // np.finfo(float32).eps
constexpr float LBF  = 1e-4f;                    // lanczos breakdown tol

#define DEV static __device__ __forceinline__

// ---------------- Threefry-2x32 (20 rounds) --------------------------------
DEV void tf2x32(unsigned k0, unsigned k1, unsigned x0, unsigned x1,
                unsigned &o0, unsigned &o1) {
  unsigned ks2 = k0 ^ k1 ^ 0x1BD11BDAu;
#define RND(r) { x0 += x1; x1 = (x1 << r) | (x1 >> (32 - r)); x1 ^= x0; }
  x0 += k0;  x1 += k1;
  RND(13) RND(15) RND(26) RND(6)
  x0 += k1;  x1 += ks2 + 1u;
  RND(17) RND(29) RND(16) RND(24)
  x0 += ks2; x1 += k0 + 2u;
  RND(13) RND(15) RND(26) RND(6)
  x0 += k0;  x1 += k1 + 3u;
  RND(17) RND(29) RND(16) RND(24)
  x0 += k1;  x1 += ks2 + 4u;
  RND(13) RND(15) RND(26) RND(6)
  x0 += ks2; x1 += k0 + 5u;
#undef RND
  o0 = x0; o1 = x1;
}

// XLA ErfInv (f32, Giles polynomial, w = -log1p(-x^2))
DEV float erfinv_f32(float x) {
  float w = -log1pf(-x * x);
  float p;
  if (w < 5.0f) {
    w -= 2.5f;
    p = 2.81022636e-08f;
    p = fmaf(p, w, 3.43273939e-07f);
    p = fmaf(p, w, -3.5233877e-06f);
    p = fmaf(p, w, -4.39150654e-06f);
    p = fmaf(p, w, 0.00021858087f);
    p = fmaf(p, w, -0.00125372503f);
    p = fmaf(p, w, -0.00417768164f);
    p = fmaf(p, w, 0.246640727f);
    p = fmaf(p, w, 1.50140941f);
  } else {
    w = sqrtf(w) - 3.0f;
    p = -0.000200214257f;
    p = fmaf(p, w, 0.000100950558f);
    p = fmaf(p, w, 0.00134934322f);
    p = fmaf(p, w, -0.00367342844f);
    p = fmaf(p, w, 0.00573950773f);
    p = fmaf(p, w, -0.0076224613f);
    p = fmaf(p, w, 0.00943887047f);
    p = fmaf(p, w, 1.00167406f);
    p = fmaf(p, w, 2.83297682f);
  }
  return p * x;
}

DEV float jax_normal(unsigned k0, unsigned k1, unsigned idx) {
  unsigned o0, o1;
  tf2x32(k0, k1, 0u /*hi*/, idx /*lo*/, o0, o1);
  unsigned bits = o0 ^ o1;
  float u = __uint_as_float((bits >> 9) | 0x3f800000u) - 1.0f;  // [0,1)
  const float lo = -0.99999994f;
  float v = fmaxf(lo, u * 2.0f + lo);
  return 1.41421356237309515f * erfinv_f32(v);
}

// ---------------- reductions ----------------------------------------------
DEV double waveRedD(double v) {
#pragma unroll
  for (int m = 32; m > 0; m >>= 1) v += __shfl_xor(v, m, 64);
  return v;
}
DEV float waveRedF(float v) {
#pragma unroll
  for (int m = 32; m > 0; m >>= 1) v += __shfl_xor(v, m, 64);
  return v;
}
DEV double blockSumD(double v, double *s4) {
  v = waveRedD(v);
  int w = threadIdx.x >> 6;
  __syncthreads();
  if ((threadIdx.x & 63) == 0) s4[w] = v;
  __syncthreads();
  return s4[0] + s4[1] + s4[2] + s4[3];
}
// dual-value 256-thread block sum (one barrier pair for two sums)
DEV void blockSumDx2(double va, double vb, double *sA, double *sB,
                     double &oa, double &ob) {
  va = waveRedD(va);
  vb = waveRedD(vb);
  int w = threadIdx.x >> 6;
  __syncthreads();
  if ((threadIdx.x & 63) == 0) { sA[w] = va; sB[w] = vb; }
  __syncthreads();
  oa = sA[0] + sA[1] + sA[2] + sA[3];
  ob = sB[0] + sB[1] + sB[2] + sB[3];
}

// ---------------- stage 1: embedding table + one-hot state ----------------
__global__ __launch_bounds__(256) void feat_table_kernel(
    const float *__restrict__ w1, const float *__restrict__ b1,
    const float *__restrict__ w2, const float *__restrict__ b2,
    float *__restrict__ table) {
  int a = blockIdx.x, t = threadIdx.x;
  __shared__ float hh[1024];
  __shared__ float part[256];
  for (int k = t; k < 1024; k += 256)
    hh[k] = fmaxf(w1[(size_t)a * 1024 + k] + b1[k], 0.f);
  __syncthreads();
  int d = t & 63, slice = t >> 6;
  float acc = 0.f;
  for (int k = slice * 256; k < slice * 256 + 256; k++)
    acc += hh[k] * w2[(size_t)k * 64 + d];
  part[t] = acc;
  __syncthreads();
  if (t < 64)
    table[(size_t)a * 64 + t] =
        part[t] + part[64 + t] + part[128 + t] + part[192 + t] + b2[t];
}

__global__ void feat_state_kernel(const int *__restrict__ nf,
                                  const float *__restrict__ table,
                                  float *__restrict__ feat,
                                  float *__restrict__ state0) {
  int g = blockIdx.x, t = threadIdx.x;  // 64 threads
  int a = nf[g];
  feat[(size_t)g * 64 + t] = table[(size_t)a * 64 + t];
  state0[(size_t)g * 64 + t] = (t == a) ? 1.f : 0.f;
}

// featT[b][d][n] = feat[b][n][d]  (LDS-tiled transpose, 64x64 tiles)
__global__ __launch_bounds__(256) void feat_tr_kernel(
    const float *__restrict__ feat, float *__restrict__ featT) {
  int g = blockIdx.x;           // nB*4
  int bb = g >> 2, n0 = (g & 3) * 64;
  int t = threadIdx.x;
  int c = t & 63, r4 = t >> 6;
  __shared__ float tl[64][65];
  for (int r = r4; r < 64; r += 4)
    tl[r][c] = feat[((size_t)(bb * nN + n0 + r)) * 64 + c];
  __syncthreads();
  for (int r = r4; r < 64; r += 4)
    featT[(size_t)bb * 16384 + (size_t)r * nN + n0 + c] = tl[c][r];
}

// ---------------- stage 2: graph laplacian --------------------------------
__global__ __launch_bounds__(256) void dist2_kernel(
    const float *__restrict__ feat, const float *__restrict__ featT,
    float *__restrict__ G, double *__restrict__ part) {
  int g = blockIdx.x;             // nB*64
  int bb = g >> 6, i0 = (g & 63) * 4;
  int t = threadIdx.x;
  __shared__ float fi[4][64];
  __shared__ double s4[4];
  {
    int r = t >> 6, d = t & 63;
    fi[r][d] = feat[((size_t)(bb * nN + i0 + r)) * 64 + d];
  }
  __syncthreads();
  const float *ft = featT + (size_t)bb * 16384 + t;
  float a0 = 0.f, a1 = 0.f, a2 = 0.f, a3 = 0.f;
#pragma unroll 8
  for (int d = 0; d < 64; d++) {
    float x = ft[(size_t)d * nN];
    float d0 = fi[0][d] - x; a0 += d0 * d0;
    float d1 = fi[1][d] - x; a1 += d1 * d1;
    float d2 = fi[2][d] - x; a2 += d2 * d2;
    float d3 = fi[3][d] - x; a3 += d3 * d3;
  }
  size_t base = ((size_t)bb * nN + i0) * nN + t;
  G[base]           = a0;
  G[base + nN]      = a1;
  G[base + 2 * nN]  = a2;
  G[base + 3 * nN]  = a3;
  double tot = blockSumD((double)a0 + (double)a1 + (double)a2 + (double)a3, s4);
  if (t == 0) part[g] = tot;
}

__global__ __launch_bounds__(64) void sigred_kernel(
    const double *__restrict__ part, float *__restrict__ sigma2) {
  int bb = blockIdx.x, t = threadIdx.x;
  double v = part[(size_t)bb * 64 + t];
  v = waveRedD(v);
  if (t == 0) sigma2[bb] = (float)(v / 65536.0);
}

__global__ __launch_bounds__(256) void arow_kernel(
    const float *__restrict__ Lfull, const float *__restrict__ sigma2,
    float *__restrict__ G, float *__restrict__ Dv) {
  int g = blockIdx.x;
  int i = g % nN, bb = g / nN;
  int t = threadIdx.x;
  __shared__ double s4[4];
  float sig = sigma2[bb];
  size_t idx2 = ((size_t)bb * nN + i) * nN + t;
  float a = expf(-G[idx2] / sig) * Lfull[idx2 * 4];  // adj mask = L[...,0]
  G[idx2] = a;
  double rs = blockSumD((double)a, s4);
  if (t == 0) {
    float r = (float)rs;
    float pad = (r == 0.f) ? 1.f : 0.f;
    Dv[(size_t)bb * nN + i] = 1.f / sqrtf(r + pad);
  }
}

// scale G in place AND write GT = Lk^T (tiled transpose)
__global__ __launch_bounds__(256) void lkscale_tr_kernel(
    float *__restrict__ G, const float *__restrict__ Dv,
    float *__restrict__ GT) {
  int g = blockIdx.x;                 // nB*16
  int bb = g >> 4, tile = g & 15;
  int ti = (tile >> 2) * 64, tj = (tile & 3) * 64;
  int t = threadIdx.x;
  int lj = t & 63, li0 = t >> 6;
  __shared__ float tl[64][65];
  for (int r = li0; r < 64; r += 4) {
    int i = ti + r;
    size_t idx = ((size_t)bb * nN + i) * nN + tj + lj;
    float v = Dv[(size_t)bb * nN + i] * G[idx] * Dv[(size_t)bb * nN + tj + lj];
    G[idx] = v;
    tl[r][lj] = v;
  }
  __syncthreads();
  for (int r = li0; r < 64; r += 4) {
    int j = tj + r;
    GT[((size_t)bb * nN + j) * nN + ti + lj] = tl[lj][r];
  }
}

// ---------------- stage 3: Lanczos (256 threads, one row per thread) ------
// Thread t holds row t of Lk in VGPRs (256 regs). waves_per_eu(1,1) forces
// the compiler to allow up to 512 VGPRs/wave (1 wave/SIMD = our 16 blocks on
// 256 CUs anyway). Matvec z[t] = row.qc is thread-local: no reduction.
__global__ __launch_bounds__(256)
__attribute__((amdgpu_waves_per_eu(1, 1)))
void lanczos_kernel(const float *__restrict__ GT, float *__restrict__ Qout,
                    float *__restrict__ Tout) {
  __shared__ float Qb[nK * nN];          // [k][n]  20 KiB
  __shared__ float qc[nN], qp[nN], zz[nN];
  __shared__ float qn2[nK], sAl[nK], sBe[nK], sVa[nK], coef[nK];
  __shared__ double s4[4], s4b[4];
  int bb = blockIdx.x, t = threadIdx.x;
  int wv = t >> 6, lane = t & 63;

  // row t of Lk = column t of GT: GT[j*256+t] is coalesced across t.
  float row[nN];
  const float *Gp = GT + (size_t)bb * (nN * nN) + t;
#pragma unroll
  for (int j = 0; j < nN; j++) row[j] = Gp[(size_t)j * nN];

  // q0 = normal(fold_in(key(42),0), (B,N)); q0 /= ||q0||
  unsigned k0, k1;
  tf2x32(0u, 42u, 0u, 0u, k0, k1);
  float val = jax_normal(k0, k1, (unsigned)(bb * nN + t));
  double n2 = blockSumD((double)val * (double)val, s4);
  float nrm = sqrtf((float)n2);
  qc[t] = val / nrm;
  qp[t] = 0.f;
  __syncthreads();

  float beta_prev = 0.f, validf = 1.f;

  for (int i = 0; i < nK; i++) {
    // z[t] = row . qc  (VGPR x LDS-broadcast; same f64 grouping as round 2)
    double a0 = 0, a1 = 0, a2 = 0, a3 = 0, a4 = 0, a5 = 0, a6 = 0, a7 = 0;
#pragma unroll
    for (int j = 0; j < nN; j += 8) {
      a0 += (double)row[j + 0] * (double)qc[j + 0];
      a1 += (double)row[j + 1] * (double)qc[j + 1];
      a2 += (double)row[j + 2] * (double)qc[j + 2];
      a3 += (double)row[j + 3] * (double)qc[j + 3];
      a4 += (double)row[j + 4] * (double)qc[j + 4];
      a5 += (double)row[j + 5] * (double)qc[j + 5];
      a6 += (double)row[j + 6] * (double)qc[j + 6];
      a7 += (double)row[j + 7] * (double)qc[j + 7];
    }
    float zi = (float)(((a0 + a1) + (a2 + a3)) + ((a4 + a5) + (a6 + a7)));
    // alpha
    double ad = blockSumD((double)qc[t] * (double)zi, s4);
    float alpha = (float)ad;
    zi = zi - alpha * qc[t] - beta_prev * qp[t];
    zz[t] = zi;
    __syncthreads();
    // double block reorthogonalization against Q[:, :i]
    for (int pass = 0; pass < 2; pass++) {
      for (int k = wv; k < i; k += 4) {
        double p = 0.0;
        for (int n0 = lane; n0 < nN; n0 += 64)
          p += (double)Qb[k * nN + n0] * (double)zz[n0];
        p = waveRedD(p);
        if (lane == 0)
          coef[k] = (float)(p / ((double)qn2[k] + (double)EPSF));
      }
      __syncthreads();
      double sub = 0.0;
      for (int k = 0; k < i; k++)
        sub += (double)Qb[k * nN + t] * (double)coef[k];
      float znew = (float)((double)zz[t] - sub);
      zz[t] = znew;   // safe: other threads only re-read zz after the barrier
      __syncthreads();
    }
    // beta and ||qc||^2 in one dual reduction
    float zfin = zz[t];
    double b2, q2;
    blockSumDx2((double)zfin * (double)zfin, (double)qc[t] * (double)qc[t],
                s4, s4b, b2, q2);
    float beta = sqrtf((float)b2);
    validf *= (beta >= LBF) ? 1.f : 0.f;
    Qb[i * nN + t] = qc[t];
    if (t == 0) {
      qn2[i] = (float)q2;
      sAl[i] = alpha;
      sBe[i] = beta;
      sVa[i] = validf;
    }
    __syncthreads();
    float qnext = zfin * validf / (beta + EPSF);
    qp[t] = qc[t];
    qc[t] = qnext;
    __syncthreads();
    beta_prev = beta;
  }

  // idx = sum(valid); mask Q rows/cols; build T
  float idxf = 0.f;
  for (int k = 0; k < nK; k++) idxf += sVa[k];
  int idx = (int)idxf;
  float rowok = ((t < idx) || (idx >= nN)) ? 1.f : 0.f;
  for (int k = 0; k < nK; k++)
    Qout[((size_t)bb * nN + t) * nK + k] = Qb[k * nN + t] * sVa[k] * rowok;
  for (int e = t; e < nK * nK; e += 256) {
    int i = e / nK, j = e % nK;
    float v = 0.f;
    if (i == j) v = sAl[i] * sVa[i];
    else if (j == i + 1) v = sBe[i] * sVa[i];
    else if (i == j + 1) v = sBe[j] * sVa[j];
    Tout[(size_t)bb * nK * nK + e] = v;
  }
}

// ---------------- stage 4: gated T powers (per batch) ----------------------
__global__ __launch_bounds__(64) void spect_power_kernel(
    const float *__restrict__ Tin, float *__restrict__ Tpow, int fold_data) {
  __shared__ float T_[nK * nK], TT[nK * nK], TTn[nK * nK];
  __shared__ float Tb[nK], Tbn[nK];
  int bb = blockIdx.x, t = threadIdx.x;
  for (int e = t; e < nK * nK; e += 64) {
    float v = Tin[(size_t)bb * nK * nK + e];
    T_[e] = v;
    TT[e] = v;
  }
  unsigned k0, k1;
  tf2x32(0u, 42u, 0u, (unsigned)fold_data, k0, k1);
  if (t < nK) Tb[t] = jax_normal(k0, k1, (unsigned)(bb * nK + t));
  __syncthreads();
  float pv = (t < nK) ? Tb[t] * Tb[t] : 0.f;
  float nb = sqrtf(waveRedF(pv));
  if (t < nK) Tb[t] = Tb[t] / nb;
  __syncthreads();
  for (int ii = 0; ii < 8; ii++) {
    if (ii == 3 || ii == 5 || ii == 7) {
      int s = (ii - 3) / 2;
      for (int e = t; e < nK * nK; e += 64)
        Tpow[((size_t)s * nB + bb) * nK * nK + e] = TT[e];
    }
    __syncthreads();
    for (int e = t; e < nK * nK; e += 64) {
      int i = e / nK, j = e % nK;
      float a = 0.f;
      for (int l = 0; l < nK; l++) a += TT[i * nK + l] * T_[l * nK + j];
      TTn[e] = a;
    }
    if (t < nK) {
      float a = 0.f;
      for (int l = 0; l < nK; l++) a += T_[t * nK + l] * Tb[l];
      Tbn[t] = a;
    }
    __syncthreads();
    float pn = (t < nK) ? Tbn[t] * Tb[t] : 0.f;
    float pd = (t < nK) ? Tb[t] * Tb[t] : 0.f;
    float num = waveRedF(pn);
    float den = waveRedF(pd);
    float lmax = num / (den + EPSF);
    float keep = (fabsf(lmax) <= 1.0f) ? 1.f : 0.f;
    __syncthreads();
    for (int e = t; e < nK * nK; e += 64) TT[e] = TTn[e] * keep;
    float p2 = (t < nK) ? Tbn[t] * Tbn[t] : 0.f;
    float nn = sqrtf(waveRedF(p2));
    if (t < nK) Tb[t] = Tbn[t] / (nn + EPSF);
    __syncthreads();
  }
}

// ---------------- stage 4b: eigen maps ------------------------------------
__global__ __launch_bounds__(256) void eig1_kernel(
    const float *__restrict__ Tpow, const float *__restrict__ w1p,
    const float *__restrict__ b1p, float *__restrict__ h) {
  int g = blockIdx.x;                 // 3*B*4 blocks
  int chunk = g & 3, bb = (g >> 2) % nB, s = g / (4 * nB);
  int t = threadIdx.x;
  __shared__ float tp[nK * nK];
  for (int e = t; e < nK * nK; e += 256)
    tp[e] = Tpow[((size_t)s * nB + bb) * nK * nK + e];
  __syncthreads();
  int o = chunk * 256 + t;
  const float *W = w1p + (size_t)s * 400 * 1024;
  float acc = b1p[(size_t)s * 1024 + o];
  for (int k = 0; k < 400; k++) acc += tp[k] * W[(size_t)k * 1024 + o];
  h[((size_t)s * nB + bb) * 1024 + o] = fmaxf(acc, 0.f);
}

__global__ __launch_bounds__(256) void eig2_kernel(
    const float *__restrict__ h, const float *__restrict__ w2p,
    const float *__restrict__ b2p, float *__restrict__ DD) {
  int g = blockIdx.x;  // 3*B blocks
  int bb = g % nB, s = g / nB;
  int t = threadIdx.x;
  __shared__ float hh[1024];
  __shared__ float raw[nK * nK];
  for (int e = t; e < 1024; e += 256)
    hh[e] = h[((size_t)s * nB + bb) * 1024 + e];
  __syncthreads();
  const float *W = w2p + (size_t)s * 1024 * 400;
  for (int kl = t; kl < 400; kl += 256) {
    float acc = b2p[(size_t)s * 400 + kl];
    for (int o = 0; o < 1024; o++) acc += hh[o] * W[(size_t)o * 400 + kl];
    raw[kl] = acc;
  }
  __syncthreads();
  for (int e = t; e < 400; e += 256) {
    int i = e / nK, j = e % nK;
    int mi = i < j ? i : j, ma = i < j ? j : i;
    DD[((size_t)s * nB + bb) * 400 + e] = raw[mi * nK + ma];
  }
}

// ---------------- stage 5: message assembly -------------------------------
__global__ void qtstate_kernel(const float *__restrict__ Q,
                               const float *__restrict__ state,
                               float *__restrict__ E) {
  int g = blockIdx.x;
  int k = g % nK, bb = g / nK;
  int t = threadIdx.x, Din = blockDim.x;
  __shared__ float qcol[nN];
  for (int n = t; n < nN; n += Din) qcol[n] = Q[((size_t)bb * nN + n) * nK + k];
  __syncthreads();
  const float *st = state + (size_t)bb * nN * Din;
  float acc = 0.f;
  for (int n = 0; n < nN; n++) acc += qcol[n] * st[(size_t)n * Din + t];
  E[((size_t)bb * nK + k) * Din + t] = acc;
}

__global__ void ddE_kernel(const float *__restrict__ DD,
                           const float *__restrict__ E,
                           float *__restrict__ F) {
  int g = blockIdx.x;
  int k = g % nK, bb = (g / nK) % nB, s = g / (nK * nB);
  int t = threadIdx.x, Din = blockDim.x;
  __shared__ float dr[nK];
  if (t < nK) dr[t] = DD[((size_t)s * nB + bb) * 400 + k * nK + t];
  __syncthreads();
  float acc = 0.f;
  for (int l = 0; l < nK; l++)
    acc += dr[l] * E[((size_t)bb * nK + l) * Din + t];
  F[(((size_t)s * nB + bb) * nK + k) * Din + t] = acc;
}

// out = Lk @ in, 8 rows per block (rows staged in LDS, input reused 8x)
__global__ void lk_matvec_kernel(const float *__restrict__ Lk,
                                 const float *__restrict__ in, int inStride,
                                 float *__restrict__ out, int outStride) {
  int g = blockIdx.x;                 // nB*nN/8
  int bb = g >> 5, r0 = (g & 31) * 8;
  int t = threadIdx.x, Din = blockDim.x;
  __shared__ float rows[8][nN];
  for (int e = t; e < 8 * nN; e += Din) {
    int r = e >> 8, j = e & 255;
    rows[r][j] = Lk[((size_t)bb * nN + r0 + r) * nN + j];
  }
  __syncthreads();
  float acc[8] = {0.f, 0.f, 0.f, 0.f, 0.f, 0.f, 0.f, 0.f};
  const float *ip = in + (size_t)bb * nN * inStride + t;
  for (int j = 0; j < nN; j++) {
    float x = ip[(size_t)j * inStride];
#pragma unroll
    for (int r = 0; r < 8; r++) acc[r] += rows[r][j] * x;
  }
#pragma unroll
  for (int r = 0; r < 8; r++)
    out[((size_t)bb * nN + r0 + r) * outStride + t] = acc[r];
}

// msg parts 3..5: Q @ F[s]
__global__ void longmsg_kernel(const float *__restrict__ Q,
                               const float *__restrict__ F,
                               float *__restrict__ msg, int C) {
  int g = blockIdx.x;
  int i = g % nN, bb = g / nN;
  int t = threadIdx.x, Din = blockDim.x;
  __shared__ float qr[nK];
  if (t < nK) qr[t] = Q[((size_t)bb * nN + i) * nK + t];
  __syncthreads();
  for (int s = 0; s < 3; s++) {
    float acc = 0.f;
    for (int k = 0; k < nK; k++)
      acc += qr[k] * F[(((size_t)s * nB + bb) * nK + k) * Din + t];
    msg[((size_t)bb * nN + i) * C + (3 + s) * Din + t] = acc;
  }
}

// msg parts 6..9: L[...,e] @ state, 4 rows/block, float4 over the 4 edgetypes
__global__ void edgemsg_kernel(const float *__restrict__ Lfull,
                               const float *__restrict__ state,
                               float *__restrict__ msg, int C) {
  int g = blockIdx.x;                 // nB*nN/4
  int bb = g >> 6, r0 = (g & 63) * 4;
  int t = threadIdx.x, Din = blockDim.x;
  __shared__ float4 rows4[4][nN];     // 16 KiB
  const float4 *L4 = (const float4 *)Lfull;
  for (int e = t; e < 4 * nN; e += Din) {
    int r = e >> 8, j = e & 255;
    rows4[r][j] = L4[((size_t)bb * nN + r0 + r) * nN + j];
  }
  __syncthreads();
  float acc[4][4];
#pragma unroll
  for (int r = 0; r < 4; r++)
#pragma unroll
    for (int e = 0; e < 4; e++) acc[r][e] = 0.f;
  const float *st = state + (size_t)bb * nN * Din + t;
  for (int j = 0; j < nN; j++) {
    float x = st[(size_t)j * Din];
#pragma unroll
    for (int r = 0; r < 4; r++) {
      float4 lv = rows4[r][j];
      acc[r][0] += lv.x * x;
      acc[r][1] += lv.y * x;
      acc[r][2] += lv.z * x;
      acc[r][3] += lv.w * x;
    }
  }
#pragma unroll
  for (int r = 0; r < 4; r++)
#pragma unroll
    for (int e = 0; e < 4; e++)
      msg[((size_t)bb * nN + r0 + r) * C + (6 + e) * Din + t] = acc[r][e];
}

// state_next = relu(msg @ W + b); 16 rows per block to amortize W reads
__global__ __launch_bounds__(256) void filt_kernel(
    const float *__restrict__ msg, const float *__restrict__ W,
    const float *__restrict__ bias, float *__restrict__ out, int C) {
  int g = blockIdx.x;                 // (B*N)/16
  int base = g * 16;
  int t = threadIdx.x;
  int o = t & 127, ih = t >> 7;       // ih: 0/1 -> rows 0..7 / 8..15
  __shared__ float mt[16][64];
  float acc[8];
  float bo = bias[o];
#pragma unroll
  for (int r = 0; r < 8; r++) acc[r] = bo;
  for (int c0 = 0; c0 < C; c0 += 64) {
    __syncthreads();
    for (int e = t; e < 16 * 64; e += 256) {
      int r = e >> 6, c = e & 63;
      mt[r][c] = msg[((size_t)(base + r)) * C + c0 + c];
    }
    __syncthreads();
    for (int c = 0; c < 64; c++) {
      float w = W[(size_t)(c0 + c) * 128 + o];
#pragma unroll
      for (int r = 0; r < 8; r++) acc[r] += mt[ih * 8 + r][c] * w;
    }
  }
#pragma unroll
  for (int r = 0; r < 8; r++)
    out[((size_t)(base + ih * 8 + r)) * 128 + o] = fmaxf(acc[r], 0.f);
}

// ---------------- stage 6: readout ----------------------------------------
__global__ __launch_bounds__(256) void score_kernel(
    const float *__restrict__ state, const float *__restrict__ wo,
    const float *__restrict__ bo, const float *__restrict__ aw,
    const float *__restrict__ ab, float *__restrict__ out) {
  __shared__ double s4[4];
  int bb = blockIdx.x, t = threadIdx.x;
  const float *st = state + ((size_t)bb * nN + t) * 128;
  float sy = bo[0], sa = ab[0];
  for (int o = 0; o < 128; o++) {
    float v = st[o];
    sy += v * wo[o];
    sa += v * aw[o];
  }
  float att = 1.f / (1.f + expf(-sa));
  double m = blockSumD((double)(att * sy), s4);
  if (t == 0) out[bb] = (float)(m / (double)nN);
}

// ---------------------------------------------------------------------------
extern "C" void kernel_launch(void *const *d_in, const int *in_sizes, int n_in,
                              void *d_out, int out_size, void *d_ws,
                              size_t ws_size, hipStream_t stream) {
  (void)in_sizes; (void)n_in; (void)out_size;
  const int   *node_feat = (const int *)d_in[0];
  const float *Lfull     = (const float *)d_in[1];
  const float *emb_w1    = (const float *)d_in[2];
  const float *emb_b1    = (const float *)d_in[3];
  const float *emb_w2    = (const float *)d_in[4];
  const float *emb_b2    = (const float *)d_in[5];
  const float *eig_w1    = (const float *)d_in[6];
  const float *eig_b1    = (const float *)d_in[7];
  const float *eig_w2    = (const float *)d_in[8];
  const float *eig_b2    = (const float *)d_in[9];
  const float *filt_w0   = (const float *)d_in[10];
  const float *filt_b0   = (const float *)d_in[11];
  const float *filt_w1   = (const float *)d_in[12];
  const float *filt_b1   = (const float *)d_in[13];
  const float *filt_wo   = (const float *)d_in[14];
  const float *filt_bo   = (const float *)d_in[15];
  const float *att_w     = (const float *)d_in[16];
  const float *att_b     = (const float *)d_in[17];

  // workspace layout (floats)
  float *ws   = (float *)d_ws;
  float *G    = ws;                    // B*N*N           = 1048576
  float *msg  = G + 1048576;           // B*N*1280        = 5242880
  float *st0  = msg + 5242880;         // B*N*64
  float *st1  = st0 + 262144;          // B*N*128
  float *st2  = st1 + 524288;          // B*N*128
  float *feat = st2 + 524288;          // B*N*64
  float *table= feat + 262144;         // 64*64
  float *Q    = table + 4096;          // B*N*K
  float *T    = Q + 81920;             // B*K*K
  float *Tpow = T + 6400;              // 3*B*K*K
  float *DD   = Tpow + 19200;          // 3*B*K*K
  float *h    = DD + 19200;            // 3*B*1024
  float *E    = h + 49152;             // B*K*128
  float *F    = E + 40960;             // 3*B*K*128
  float *Dv   = F + 122880;            // B*N
  double *part   = (double *)(Dv + 4096);   // B*N doubles (8-byte aligned)
  float  *sigma2 = (float *)(part + nB * nN);
  // GT and featT alias the msg region (both dead before msg is written)
  float *GT    = msg;                  // B*N*N = 1048576 floats
  float *featT = msg + 1048576;        // B*64*256 = 262144 floats
  const size_t needBytes = (size_t)(8220432) * 4;
  if (ws_size < needBytes) return;

  // embedding + one-hot state
  feat_table_kernel<<<64, 256, 0, stream>>>(emb_w1, emb_b1, emb_w2, emb_b2, table);
  feat_state_kernel<<<nB * nN, 64, 0, stream>>>(node_feat, table, feat, st0);
  feat_tr_kernel<<<nB * 4, 256, 0, stream>>>(feat, featT);
  // laplacian
  dist2_kernel<<<nB * 64, 256, 0, stream>>>(feat, featT, G, part);
  sigred_kernel<<<nB, 64, 0, stream>>>(part, sigma2);
  arow_kernel<<<nB * nN, 256, 0, stream>>>(Lfull, sigma2, G, Dv);
  lkscale_tr_kernel<<<nB * 16, 256, 0, stream>>>(G, Dv, GT);
  // lanczos (one matrix row per thread, register-resident)
  lanczos_kernel<<<nB, 256, 0, stream>>>(GT, Q, T);

  const float *stateIn = st0;
  float *stOut[2] = {st1, st2};
  int Din = 64;
  for (int tt = 0; tt < 2; tt++) {
    int C = 10 * Din;
    spect_power_kernel<<<nB, 64, 0, stream>>>(T, Tpow, tt + 1);
    eig1_kernel<<<3 * nB * 4, 256, 0, stream>>>(Tpow, eig_w1, eig_b1, h);
    eig2_kernel<<<3 * nB, 256, 0, stream>>>(h, eig_w2, eig_b2, DD);
    qtstate_kernel<<<nB * nK, Din, 0, stream>>>(Q, stateIn, E);
    ddE_kernel<<<3 * nB * nK, Din, 0, stream>>>(DD, E, F);
    // short diffusion chain -> parts 0..2
    lk_matvec_kernel<<<nB * nN / 8, Din, 0, stream>>>(G, stateIn, Din, msg + 0 * Din, C);
    lk_matvec_kernel<<<nB * nN / 8, Din, 0, stream>>>(G, msg + 0 * Din, C, msg + 1 * Din, C);
    lk_matvec_kernel<<<nB * nN / 8, Din, 0, stream>>>(G, msg + 1 * Din, C, msg + 2 * Din, C);
    // long spectral -> parts 3..5
    longmsg_kernel<<<nB * nN, Din, 0, stream>>>(Q, F, msg, C);
    // edge types -> parts 6..9
    edgemsg_kernel<<<nB * nN / 4, Din, 0, stream>>>(Lfull, stateIn, msg, C);
    // filter layer
    filt_kernel<<<nB * nN / 16, 256, 0, stream>>>(
        msg, tt ? filt_w1 : filt_w0, tt ? filt_b1 : filt_b0, stOut[tt], C);
    stateIn = stOut[tt];
    Din = 128;
  }
  score_kernel<<<nB, 256, 0, stream>>>(st2, filt_wo, filt_bo, att_w, att_b,
                                       (float *)d_out);
}

// Round 6
// 873.523 us; speedup vs baseline: 1.1662x; 1.0297x over previous
//
#include <hip/hip_runtime.h>

// ---------------------------------------------------------------------------
// AdaLanczosNet forward, faithful f32 re-implementation of the JAX reference.
// B=16, N=256, NUM_ATOM=64, K=20, HIDDEN=(128,128), SCALES=10.
// Round 6: lanczos = 512 threads, HALF a matrix row per thread (128 VGPRs --
// fits under the 256 architected-VGPR ISA ceiling that round 5 hit; r5 spilled
// 42 floats/thread to scratch). Reorth coefficients via 32x 16-lane groups:
// all k in ONE parallel round instead of sequential per-wave chains.
// ---------------------------------------------------------------------------

constexpr int nB = 16;
constexpr int nN = 256;
constexpr int nK = 20;
constexpr float EPSF = 1.1920928955078125e-07f;  // np.finfo(float32).eps
constexpr float LBF  = 1e-4f;                    // lanczos breakdown tol

#define DEV static __device__ __forceinline__

// ---------------- Threefry-2x32 (20 rounds) --------------------------------
DEV void tf2x32(unsigned k0, unsigned k1, unsigned x0, unsigned x1,
                unsigned &o0, unsigned &o1) {
  unsigned ks2 = k0 ^ k1 ^ 0x1BD11BDAu;
#define RND(r) { x0 += x1; x1 = (x1 << r) | (x1 >> (32 - r)); x1 ^= x0; }
  x0 += k0;  x1 += k1;
  RND(13) RND(15) RND(26) RND(6)
  x0 += k1;  x1 += ks2 + 1u;
  RND(17) RND(29) RND(16) RND(24)
  x0 += ks2; x1 += k0 + 2u;
  RND(13) RND(15) RND(26) RND(6)
  x0 += k0;  x1 += k1 + 3u;
  RND(17) RND(29) RND(16) RND(24)
  x0 += k1;  x1 += ks2 + 4u;
  RND(13) RND(15) RND(26) RND(6)
  x0 += ks2; x1 += k0 + 5u;
#undef RND
  o0 = x0; o1 = x1;
}

// XLA ErfInv (f32, Giles polynomial, w = -log1p(-x^2))
DEV float erfinv_f32(float x) {
  float w = -log1pf(-x * x);
  float p;
  if (w < 5.0f) {
    w -= 2.5f;
    p = 2.81022636e-08f;
    p = fmaf(p, w, 3.43273939e-07f);
    p = fmaf(p, w, -3.5233877e-06f);
    p = fmaf(p, w, -4.39150654e-06f);
    p = fmaf(p, w, 0.00021858087f);
    p = fmaf(p, w, -0.00125372503f);
    p = fmaf(p, w, -0.00417768164f);
    p = fmaf(p, w, 0.246640727f);
    p = fmaf(p, w, 1.50140941f);
  } else {
    w = sqrtf(w) - 3.0f;
    p = -0.000200214257f;
    p = fmaf(p, w, 0.000100950558f);
    p = fmaf(p, w, 0.00134934322f);
    p = fmaf(p, w, -0.00367342844f);
    p = fmaf(p, w, 0.00573950773f);
    p = fmaf(p, w, -0.0076224613f);
    p = fmaf(p, w, 0.00943887047f);
    p = fmaf(p, w, 1.00167406f);
    p = fmaf(p, w, 2.83297682f);
  }
  return p * x;
}

DEV float jax_normal(unsigned k0, unsigned k1, unsigned idx) {
  unsigned o0, o1;
  tf2x32(k0, k1, 0u /*hi*/, idx /*lo*/, o0, o1);
  unsigned bits = o0 ^ o1;
  float u = __uint_as_float((bits >> 9) | 0x3f800000u) - 1.0f;  // [0,1)
  const float lo = -0.99999994f;
  float v = fmaxf(lo, u * 2.0f + lo);
  return 1.41421356237309515f * erfinv_f32(v);
}

// ---------------- reductions ----------------------------------------------
DEV double waveRedD(double v) {
#pragma unroll
  for (int m = 32; m > 0; m >>= 1) v += __shfl_xor(v, m, 64);
  return v;
}
DEV float waveRedF(float v) {
#pragma unroll
  for (int m = 32; m > 0; m >>= 1) v += __shfl_xor(v, m, 64);
  return v;
}
DEV double blockSumD(double v, double *s4) {
  v = waveRedD(v);
  int w = threadIdx.x >> 6;
  __syncthreads();
  if ((threadIdx.x & 63) == 0) s4[w] = v;
  __syncthreads();
  return s4[0] + s4[1] + s4[2] + s4[3];
}
// 512-thread block sum (8 waves)
DEV double blockSum8(double v, double *red8) {
  v = waveRedD(v);
  __syncthreads();
  if ((threadIdx.x & 63) == 0) red8[threadIdx.x >> 6] = v;
  __syncthreads();
  return ((red8[0] + red8[1]) + (red8[2] + red8[3])) +
         ((red8[4] + red8[5]) + (red8[6] + red8[7]));
}
// dual-value 512-thread block sum
DEV void blockSum8x2(double va, double vb, double *rA, double *rB,
                     double &oa, double &ob) {
  va = waveRedD(va);
  vb = waveRedD(vb);
  __syncthreads();
  if ((threadIdx.x & 63) == 0) {
    rA[threadIdx.x >> 6] = va;
    rB[threadIdx.x >> 6] = vb;
  }
  __syncthreads();
  oa = ((rA[0] + rA[1]) + (rA[2] + rA[3])) + ((rA[4] + rA[5]) + (rA[6] + rA[7]));
  ob = ((rB[0] + rB[1]) + (rB[2] + rB[3])) + ((rB[4] + rB[5]) + (rB[6] + rB[7]));
}

// ---------------- stage 1: embedding table + one-hot state ----------------
__global__ __launch_bounds__(256) void feat_table_kernel(
    const float *__restrict__ w1, const float *__restrict__ b1,
    const float *__restrict__ w2, const float *__restrict__ b2,
    float *__restrict__ table) {
  int a = blockIdx.x, t = threadIdx.x;
  __shared__ float hh[1024];
  __shared__ float part[256];
  for (int k = t; k < 1024; k += 256)
    hh[k] = fmaxf(w1[(size_t)a * 1024 + k] + b1[k], 0.f);
  __syncthreads();
  int d = t & 63, slice = t >> 6;
  float acc = 0.f;
  for (int k = slice * 256; k < slice * 256 + 256; k++)
    acc += hh[k] * w2[(size_t)k * 64 + d];
  part[t] = acc;
  __syncthreads();
  if (t < 64)
    table[(size_t)a * 64 + t] =
        part[t] + part[64 + t] + part[128 + t] + part[192 + t] + b2[t];
}

__global__ void feat_state_kernel(const int *__restrict__ nf,
                                  const float *__restrict__ table,
                                  float *__restrict__ feat,
                                  float *__restrict__ state0) {
  int g = blockIdx.x, t = threadIdx.x;  // 64 threads
  int a = nf[g];
  feat[(size_t)g * 64 + t] = table[(size_t)a * 64 + t];
  state0[(size_t)g * 64 + t] = (t == a) ? 1.f : 0.f;
}

// featT[b][d][n] = feat[b][n][d]  (LDS-tiled transpose, 64x64 tiles)
__global__ __launch_bounds__(256) void feat_tr_kernel(
    const float *__restrict__ feat, float *__restrict__ featT) {
  int g = blockIdx.x;           // nB*4
  int bb = g >> 2, n0 = (g & 3) * 64;
  int t = threadIdx.x;
  int c = t & 63, r4 = t >> 6;
  __shared__ float tl[64][65];
  for (int r = r4; r < 64; r += 4)
    tl[r][c] = feat[((size_t)(bb * nN + n0 + r)) * 64 + c];
  __syncthreads();
  for (int r = r4; r < 64; r += 4)
    featT[(size_t)bb * 16384 + (size_t)r * nN + n0 + c] = tl[c][r];
}

// ---------------- stage 2: graph laplacian --------------------------------
__global__ __launch_bounds__(256) void dist2_kernel(
    const float *__restrict__ feat, const float *__restrict__ featT,
    float *__restrict__ G, double *__restrict__ part) {
  int g = blockIdx.x;             // nB*64
  int bb = g >> 6, i0 = (g & 63) * 4;
  int t = threadIdx.x;
  __shared__ float fi[4][64];
  __shared__ double s4[4];
  {
    int r = t >> 6, d = t & 63;
    fi[r][d] = feat[((size_t)(bb * nN + i0 + r)) * 64 + d];
  }
  __syncthreads();
  const float *ft = featT + (size_t)bb * 16384 + t;
  float a0 = 0.f, a1 = 0.f, a2 = 0.f, a3 = 0.f;
#pragma unroll 8
  for (int d = 0; d < 64; d++) {
    float x = ft[(size_t)d * nN];
    float d0 = fi[0][d] - x; a0 += d0 * d0;
    float d1 = fi[1][d] - x; a1 += d1 * d1;
    float d2 = fi[2][d] - x; a2 += d2 * d2;
    float d3 = fi[3][d] - x; a3 += d3 * d3;
  }
  size_t base = ((size_t)bb * nN + i0) * nN + t;
  G[base]           = a0;
  G[base + nN]      = a1;
  G[base + 2 * nN]  = a2;
  G[base + 3 * nN]  = a3;
  double tot = blockSumD((double)a0 + (double)a1 + (double)a2 + (double)a3, s4);
  if (t == 0) part[g] = tot;
}

__global__ __launch_bounds__(64) void sigred_kernel(
    const double *__restrict__ part, float *__restrict__ sigma2) {
  int bb = blockIdx.x, t = threadIdx.x;
  double v = part[(size_t)bb * 64 + t];
  v = waveRedD(v);
  if (t == 0) sigma2[bb] = (float)(v / 65536.0);
}

__global__ __launch_bounds__(256) void arow_kernel(
    const float *__restrict__ Lfull, const float *__restrict__ sigma2,
    float *__restrict__ G, float *__restrict__ Dv) {
  int g = blockIdx.x;
  int i = g % nN, bb = g / nN;
  int t = threadIdx.x;
  __shared__ double s4[4];
  float sig = sigma2[bb];
  size_t idx2 = ((size_t)bb * nN + i) * nN + t;
  float a = expf(-G[idx2] / sig) * Lfull[idx2 * 4];  // adj mask = L[...,0]
  G[idx2] = a;
  double rs = blockSumD((double)a, s4);
  if (t == 0) {
    float r = (float)rs;
    float pad = (r == 0.f) ? 1.f : 0.f;
    Dv[(size_t)bb * nN + i] = 1.f / sqrtf(r + pad);
  }
}

// scale G in place AND write GT = Lk^T (tiled transpose)
__global__ __launch_bounds__(256) void lkscale_tr_kernel(
    float *__restrict__ G, const float *__restrict__ Dv,
    float *__restrict__ GT) {
  int g = blockIdx.x;                 // nB*16
  int bb = g >> 4, tile = g & 15;
  int ti = (tile >> 2) * 64, tj = (tile & 3) * 64;
  int t = threadIdx.x;
  int lj = t & 63, li0 = t >> 6;
  __shared__ float tl[64][65];
  for (int r = li0; r < 64; r += 4) {
    int i = ti + r;
    size_t idx = ((size_t)bb * nN + i) * nN + tj + lj;
    float v = Dv[(size_t)bb * nN + i] * G[idx] * Dv[(size_t)bb * nN + tj + lj];
    G[idx] = v;
    tl[r][lj] = v;
  }
  __syncthreads();
  for (int r = li0; r < 64; r += 4) {
    int j = tj + r;
    GT[((size_t)bb * nN + j) * nN + ti + lj] = tl[lj][r];
  }
}

// ---------------- stage 3: Lanczos (512 threads, half-row per thread) -----
// Thread u = (h,t): holds Lk[t][h*128 .. h*128+127] in 128 VGPRs. 8 waves,
// 2/SIMD (waves_per_eu(2,2) -> 256-VGPR cap, fits with headroom, NO spill).
// Reorth: 32 16-lane groups compute all i coefficients in one parallel round.
__global__ __launch_bounds__(512)
__attribute__((amdgpu_waves_per_eu(2, 2)))
void lanczos_kernel(const float *__restrict__ GT, float *__restrict__ Qout,
                    float *__restrict__ Tout) {
  __shared__ float Qb[nK * nN];          // [k][n]  20 KiB
  __shared__ float qc[nN], qp[nN], zz[nN];
  __shared__ double zpA[nN], zpB[nN];    // matvec half-partials (4 KiB)
  __shared__ float qn2[nK], sAl[nK], sBe[nK], sVa[nK], coef[nK];
  __shared__ double red[8], redB[8];
  int bb = blockIdx.x, u = threadIdx.x;
  int t = u & 255, h = u >> 8;           // row t, half h
  int gid = u >> 4, gl = u & 15;         // 16-lane reorth groups

  // preload: rowreg[jj] = Lk[t][h*128+jj] = GT[(h*128+jj)*256 + t]
  float rowreg[128];
  const float *Gp = GT + (size_t)bb * (nN * nN) + (size_t)(h * 128) * nN + t;
#pragma unroll
  for (int jj = 0; jj < 128; jj++) rowreg[jj] = Gp[(size_t)jj * nN];

  // q0 = normal(fold_in(key(42),0), (B,N)); q0 /= ||q0||
  unsigned k0, k1;
  tf2x32(0u, 42u, 0u, 0u, k0, k1);
  float val = 0.f;
  if (h == 0) val = jax_normal(k0, k1, (unsigned)(bb * nN + t));
  double n2 = blockSum8((double)val * (double)val, red);
  if (h == 0) {
    qc[t] = val / sqrtf((float)n2);
    qp[t] = 0.f;
  }
  __syncthreads();

  float beta_prev = 0.f, validf = 1.f;

  for (int i = 0; i < nK; i++) {
    // --- z = Lk @ qc : half-row register FMAs, LDS-broadcast qc
    {
      double a0 = 0, a1 = 0, a2 = 0, a3 = 0, a4 = 0, a5 = 0, a6 = 0, a7 = 0;
      const float *qv = qc + h * 128;
#pragma unroll
      for (int jj = 0; jj < 128; jj += 8) {
        a0 += (double)rowreg[jj + 0] * (double)qv[jj + 0];
        a1 += (double)rowreg[jj + 1] * (double)qv[jj + 1];
        a2 += (double)rowreg[jj + 2] * (double)qv[jj + 2];
        a3 += (double)rowreg[jj + 3] * (double)qv[jj + 3];
        a4 += (double)rowreg[jj + 4] * (double)qv[jj + 4];
        a5 += (double)rowreg[jj + 5] * (double)qv[jj + 5];
        a6 += (double)rowreg[jj + 6] * (double)qv[jj + 6];
        a7 += (double)rowreg[jj + 7] * (double)qv[jj + 7];
      }
      double part = (((a0 + a1) + (a2 + a3)) + ((a4 + a5) + (a6 + a7)));
      if (h == 0) zpA[t] = part; else zpB[t] = part;
    }
    __syncthreads();
    float zi = 0.f;
    if (h == 0) zi = (float)(zpA[t] + zpB[t]);
    // alpha
    double ad = blockSum8((h == 0) ? (double)qc[t] * (double)zi : 0.0, red);
    float alpha = (float)ad;
    if (h == 0) {
      zi = zi - alpha * qc[t] - beta_prev * qp[t];
      zz[t] = zi;
    }
    __syncthreads();
    // --- double block reorth: ALL k in one parallel round (group per k)
    for (int pass = 0; pass < 2; pass++) {
      if (gid < i) {
        double p = 0.0;
#pragma unroll
        for (int j = 0; j < 16; j++) {
          int n0 = gl + 16 * j;
          p += (double)Qb[gid * nN + n0] * (double)zz[n0];
        }
#pragma unroll
        for (int m = 1; m <= 8; m <<= 1) p += __shfl_xor(p, m, 64);
        if (gl == 0)
          coef[gid] = (float)(p / ((double)qn2[gid] + (double)EPSF));
      }
      __syncthreads();
      if (h == 0) {
        double sub = 0.0;
        for (int k = 0; k < i; k++)
          sub += (double)Qb[k * nN + t] * (double)coef[k];
        zz[t] = (float)((double)zz[t] - sub);
      }
      __syncthreads();
    }
    // --- beta and ||qc||^2 in one dual reduction
    float zfin = (h == 0) ? zz[t] : 0.f;
    float qcv  = (h == 0) ? qc[t] : 0.f;
    double b2, q2;
    blockSum8x2((double)zfin * (double)zfin, (double)qcv * (double)qcv,
                red, redB, b2, q2);
    float beta = sqrtf((float)b2);
    validf *= (beta >= LBF) ? 1.f : 0.f;
    if (h == 0) Qb[i * nN + t] = qc[t];
    if (u == 0) {
      qn2[i] = (float)q2;
      sAl[i] = alpha;
      sBe[i] = beta;
      sVa[i] = validf;
    }
    __syncthreads();
    if (h == 0) {
      float qnext = zz[t] * validf / (beta + EPSF);
      qp[t] = qc[t];
      qc[t] = qnext;
    }
    __syncthreads();
    beta_prev = beta;
  }

  // idx = sum(valid); mask Q rows/cols; build T
  float idxf = 0.f;
  for (int k = 0; k < nK; k++) idxf += sVa[k];
  int idx = (int)idxf;
  if (h == 0) {
    float rowok = ((t < idx) || (idx >= nN)) ? 1.f : 0.f;
    for (int k = 0; k < nK; k++)
      Qout[((size_t)bb * nN + t) * nK + k] = Qb[k * nN + t] * sVa[k] * rowok;
  }
  for (int e = u; e < nK * nK; e += 512) {
    int i = e / nK, j = e % nK;
    float v = 0.f;
    if (i == j) v = sAl[i] * sVa[i];
    else if (j == i + 1) v = sBe[i] * sVa[i];
    else if (i == j + 1) v = sBe[j] * sVa[j];
    Tout[(size_t)bb * nK * nK + e] = v;
  }
}

// ---------------- stage 4: gated T powers (per batch) ----------------------
__global__ __launch_bounds__(64) void spect_power_kernel(
    const float *__restrict__ Tin, float *__restrict__ Tpow, int fold_data) {
  __shared__ float T_[nK * nK], TT[nK * nK], TTn[nK * nK];
  __shared__ float Tb[nK], Tbn[nK];
  int bb = blockIdx.x, t = threadIdx.x;
  for (int e = t; e < nK * nK; e += 64) {
    float v = Tin[(size_t)bb * nK * nK + e];
    T_[e] = v;
    TT[e] = v;
  }
  unsigned k0, k1;
  tf2x32(0u, 42u, 0u, (unsigned)fold_data, k0, k1);
  if (t < nK) Tb[t] = jax_normal(k0, k1, (unsigned)(bb * nK + t));
  __syncthreads();
  float pv = (t < nK) ? Tb[t] * Tb[t] : 0.f;
  float nb = sqrtf(waveRedF(pv));
  if (t < nK) Tb[t] = Tb[t] / nb;
  __syncthreads();
  for (int ii = 0; ii < 8; ii++) {
    if (ii == 3 || ii == 5 || ii == 7) {
      int s = (ii - 3) / 2;
      for (int e = t; e < nK * nK; e += 64)
        Tpow[((size_t)s * nB + bb) * nK * nK + e] = TT[e];
    }
    __syncthreads();
    for (int e = t; e < nK * nK; e += 64) {
      int i = e / nK, j = e % nK;
      float a = 0.f;
      for (int l = 0; l < nK; l++) a += TT[i * nK + l] * T_[l * nK + j];
      TTn[e] = a;
    }
    if (t < nK) {
      float a = 0.f;
      for (int l = 0; l < nK; l++) a += T_[t * nK + l] * Tb[l];
      Tbn[t] = a;
    }
    __syncthreads();
    float pn = (t < nK) ? Tbn[t] * Tb[t] : 0.f;
    float pd = (t < nK) ? Tb[t] * Tb[t] : 0.f;
    float num = waveRedF(pn);
    float den = waveRedF(pd);
    float lmax = num / (den + EPSF);
    float keep = (fabsf(lmax) <= 1.0f) ? 1.f : 0.f;
    __syncthreads();
    for (int e = t; e < nK * nK; e += 64) TT[e] = TTn[e] * keep;
    float p2 = (t < nK) ? Tbn[t] * Tbn[t] : 0.f;
    float nn = sqrtf(waveRedF(p2));
    if (t < nK) Tb[t] = Tbn[t] / (nn + EPSF);
    __syncthreads();
  }
}

// ---------------- stage 4b: eigen maps ------------------------------------
__global__ __launch_bounds__(256) void eig1_kernel(
    const float *__restrict__ Tpow, const float *__restrict__ w1p,
    const float *__restrict__ b1p, float *__restrict__ h) {
  int g = blockIdx.x;                 // 3*B*4 blocks
  int chunk = g & 3, bb = (g >> 2) % nB, s = g / (4 * nB);
  int t = threadIdx.x;
  __shared__ float tp[nK * nK];
  for (int e = t; e < nK * nK; e += 256)
    tp[e] = Tpow[((size_t)s * nB + bb) * nK * nK + e];
  __syncthreads();
  int o = chunk * 256 + t;
  const float *W = w1p + (size_t)s * 400 * 1024;
  float acc = b1p[(size_t)s * 1024 + o];
  for (int k = 0; k < 400; k++) acc += tp[k] * W[(size_t)k * 1024 + o];
  h[((size_t)s * nB + bb) * 1024 + o] = fmaxf(acc, 0.f);
}

__global__ __launch_bounds__(256) void eig2_kernel(
    const float *__restrict__ h, const float *__restrict__ w2p,
    const float *__restrict__ b2p, float *__restrict__ DD) {
  int g = blockIdx.x;  // 3*B blocks
  int bb = g % nB, s = g / nB;
  int t = threadIdx.x;
  __shared__ float hh[1024];
  __shared__ float raw[nK * nK];
  for (int e = t; e < 1024; e += 256)
    hh[e] = h[((size_t)s * nB + bb) * 1024 + e];
  __syncthreads();
  const float *W = w2p + (size_t)s * 1024 * 400;
  for (int kl = t; kl < 400; kl += 256) {
    float acc = b2p[(size_t)s * 400 + kl];
    for (int o = 0; o < 1024; o++) acc += hh[o] * W[(size_t)o * 400 + kl];
    raw[kl] = acc;
  }
  __syncthreads();
  for (int e = t; e < 400; e += 256) {
    int i = e / nK, j = e % nK;
    int mi = i < j ? i : j, ma = i < j ? j : i;
    DD[((size_t)s * nB + bb) * 400 + e] = raw[mi * nK + ma];
  }
}

// ---------------- stage 5: message assembly -------------------------------
__global__ void qtstate_kernel(const float *__restrict__ Q,
                               const float *__restrict__ state,
                               float *__restrict__ E) {
  int g = blockIdx.x;
  int k = g % nK, bb = g / nK;
  int t = threadIdx.x, Din = blockDim.x;
  __shared__ float qcol[nN];
  for (int n = t; n < nN; n += Din) qcol[n] = Q[((size_t)bb * nN + n) * nK + k];
  __syncthreads();
  const float *st = state + (size_t)bb * nN * Din;
  float acc = 0.f;
  for (int n = 0; n < nN; n++) acc += qcol[n] * st[(size_t)n * Din + t];
  E[((size_t)bb * nK + k) * Din + t] = acc;
}

__global__ void ddE_kernel(const float *__restrict__ DD,
                           const float *__restrict__ E,
                           float *__restrict__ F) {
  int g = blockIdx.x;
  int k = g % nK, bb = (g / nK) % nB, s = g / (nK * nB);
  int t = threadIdx.x, Din = blockDim.x;
  __shared__ float dr[nK];
  if (t < nK) dr[t] = DD[((size_t)s * nB + bb) * 400 + k * nK + t];
  __syncthreads();
  float acc = 0.f;
  for (int l = 0; l < nK; l++)
    acc += dr[l] * E[((size_t)bb * nK + l) * Din + t];
  F[(((size_t)s * nB + bb) * nK + k) * Din + t] = acc;
}

// out = Lk @ in, 8 rows per block (rows staged in LDS, input reused 8x)
__global__ void lk_matvec_kernel(const float *__restrict__ Lk,
                                 const float *__restrict__ in, int inStride,
                                 float *__restrict__ out, int outStride) {
  int g = blockIdx.x;                 // nB*nN/8
  int bb = g >> 5, r0 = (g & 31) * 8;
  int t = threadIdx.x, Din = blockDim.x;
  __shared__ float rows[8][nN];
  for (int e = t; e < 8 * nN; e += Din) {
    int r = e >> 8, j = e & 255;
    rows[r][j] = Lk[((size_t)bb * nN + r0 + r) * nN + j];
  }
  __syncthreads();
  float acc[8] = {0.f, 0.f, 0.f, 0.f, 0.f, 0.f, 0.f, 0.f};
  const float *ip = in + (size_t)bb * nN * inStride + t;
  for (int j = 0; j < nN; j++) {
    float x = ip[(size_t)j * inStride];
#pragma unroll
    for (int r = 0; r < 8; r++) acc[r] += rows[r][j] * x;
  }
#pragma unroll
  for (int r = 0; r < 8; r++)
    out[((size_t)bb * nN + r0 + r) * outStride + t] = acc[r];
}

// msg parts 3..5: Q @ F[s]
__global__ void longmsg_kernel(const float *__restrict__ Q,
                               const float *__restrict__ F,
                               float *__restrict__ msg, int C) {
  int g = blockIdx.x;
  int i = g % nN, bb = g / nN;
  int t = threadIdx.x, Din = blockDim.x;
  __shared__ float qr[nK];
  if (t < nK) qr[t] = Q[((size_t)bb * nN + i) * nK + t];
  __syncthreads();
  for (int s = 0; s < 3; s++) {
    float acc = 0.f;
    for (int k = 0; k < nK; k++)
      acc += qr[k] * F[(((size_t)s * nB + bb) * nK + k) * Din + t];
    msg[((size_t)bb * nN + i) * C + (3 + s) * Din + t] = acc;
  }
}

// msg parts 6..9: L[...,e] @ state, 4 rows/block, float4 over the 4 edgetypes
__global__ void edgemsg_kernel(const float *__restrict__ Lfull,
                               const float *__restrict__ state,
                               float *__restrict__ msg, int C) {
  int g = blockIdx.x;                 // nB*nN/4
  int bb = g >> 6, r0 = (g & 63) * 4;
  int t = threadIdx.x, Din = blockDim.x;
  __shared__ float4 rows4[4][nN];     // 16 KiB
  const float4 *L4 = (const float4 *)Lfull;
  for (int e = t; e < 4 * nN; e += Din) {
    int r = e >> 8, j = e & 255;
    rows4[r][j] = L4[((size_t)bb * nN + r0 + r) * nN + j];
  }
  __syncthreads();
  float acc[4][4];
#pragma unroll
  for (int r = 0; r < 4; r++)
#pragma unroll
    for (int e = 0; e < 4; e++) acc[r][e] = 0.f;
  const float *st = state + (size_t)bb * nN * Din + t;
  for (int j = 0; j < nN; j++) {
    float x = st[(size_t)j * Din];
#pragma unroll
    for (int r = 0; r < 4; r++) {
      float4 lv = rows4[r][j];
      acc[r][0] += lv.x * x;
      acc[r][1] += lv.y * x;
      acc[r][2] += lv.z * x;
      acc[r][3] += lv.w * x;
    }
  }
#pragma unroll
  for (int r = 0; r < 4; r++)
#pragma unroll
    for (int e = 0; e < 4; e++)
      msg[((size_t)bb * nN + r0 + r) * C + (6 + e) * Din + t] = acc[r][e];
}

// state_next = relu(msg @ W + b); 16 rows per block to amortize W reads
__global__ __launch_bounds__(256) void filt_kernel(
    const float *__restrict__ msg, const float *__restrict__ W,
    const float *__restrict__ bias, float *__restrict__ out, int C) {
  int g = blockIdx.x;                 // (B*N)/16
  int base = g * 16;
  int t = threadIdx.x;
  int o = t & 127, ih = t >> 7;       // ih: 0/1 -> rows 0..7 / 8..15
  __shared__ float mt[16][64];
  float acc[8];
  float bo = bias[o];
#pragma unroll
  for (int r = 0; r < 8; r++) acc[r] = bo;
  for (int c0 = 0; c0 < C; c0 += 64) {
    __syncthreads();
    for (int e = t; e < 16 * 64; e += 256) {
      int r = e >> 6, c = e & 63;
      mt[r][c] = msg[((size_t)(base + r)) * C + c0 + c];
    }
    __syncthreads();
    for (int c = 0; c < 64; c++) {
      float w = W[(size_t)(c0 + c) * 128 + o];
#pragma unroll
      for (int r = 0; r < 8; r++) acc[r] += mt[ih * 8 + r][c] * w;
    }
  }
#pragma unroll
  for (int r = 0; r < 8; r++)
    out[((size_t)(base + ih * 8 + r)) * 128 + o] = fmaxf(acc[r], 0.f);
}

// ---------------- stage 6: readout ----------------------------------------
__global__ __launch_bounds__(256) void score_kernel(
    const float *__restrict__ state, const float *__restrict__ wo,
    const float *__restrict__ bo, const float *__restrict__ aw,
    const float *__restrict__ ab, float *__restrict__ out) {
  __shared__ double s4[4];
  int bb = blockIdx.x, t = threadIdx.x;
  const float *st = state + ((size_t)bb * nN + t) * 128;
  float sy = bo[0], sa = ab[0];
  for (int o = 0; o < 128; o++) {
    float v = st[o];
    sy += v * wo[o];
    sa += v * aw[o];
  }
  float att = 1.f / (1.f + expf(-sa));
  double m = blockSumD((double)(att * sy), s4);
  if (t == 0) out[bb] = (float)(m / (double)nN);
}

// ---------------------------------------------------------------------------
extern "C" void kernel_launch(void *const *d_in, const int *in_sizes, int n_in,
                              void *d_out, int out_size, void *d_ws,
                              size_t ws_size, hipStream_t stream) {
  (void)in_sizes; (void)n_in; (void)out_size;
  const int   *node_feat = (const int *)d_in[0];
  const float *Lfull     = (const float *)d_in[1];
  const float *emb_w1    = (const float *)d_in[2];
  const float *emb_b1    = (const float *)d_in[3];
  const float *emb_w2    = (const float *)d_in[4];
  const float *emb_b2    = (const float *)d_in[5];
  const float *eig_w1    = (const float *)d_in[6];
  const float *eig_b1    = (const float *)d_in[7];
  const float *eig_w2    = (const float *)d_in[8];
  const float *eig_b2    = (const float *)d_in[9];
  const float *filt_w0   = (const float *)d_in[10];
  const float *filt_b0   = (const float *)d_in[11];
  const float *filt_w1   = (const float *)d_in[12];
  const float *filt_b1   = (const float *)d_in[13];
  const float *filt_wo   = (const float *)d_in[14];
  const float *filt_bo   = (const float *)d_in[15];
  const float *att_w     = (const float *)d_in[16];
  const float *att_b     = (const float *)d_in[17];

  // workspace layout (floats)
  float *ws   = (float *)d_ws;
  float *G    = ws;                    // B*N*N           = 1048576
  float *msg  = G + 1048576;           // B*N*1280        = 5242880
  float *st0  = msg + 5242880;         // B*N*64
  float *st1  = st0 + 262144;          // B*N*128
  float *st2  = st1 + 524288;          // B*N*128
  float *feat = st2 + 524288;          // B*N*64
  float *table= feat + 262144;         // 64*64
  float *Q    = table + 4096;          // B*N*K
  float *T    = Q + 81920;             // B*K*K
  float *Tpow = T + 6400;              // 3*B*K*K
  float *DD   = Tpow + 19200;          // 3*B*K*K
  float *h    = DD + 19200;            // 3*B*1024
  float *E    = h + 49152;             // B*K*128
  float *F    = E + 40960;             // 3*B*K*128
  float *Dv   = F + 122880;            // B*N
  double *part   = (double *)(Dv + 4096);   // B*N doubles (8-byte aligned)
  float  *sigma2 = (float *)(part + nB * nN);
  // GT and featT alias the msg region (both dead before msg is written)
  float *GT    = msg;                  // B*N*N = 1048576 floats
  float *featT = msg + 1048576;        // B*64*256 = 262144 floats
  const size_t needBytes = (size_t)(8220432) * 4;
  if (ws_size < needBytes) return;

  // embedding + one-hot state
  feat_table_kernel<<<64, 256, 0, stream>>>(emb_w1, emb_b1, emb_w2, emb_b2, table);
  feat_state_kernel<<<nB * nN, 64, 0, stream>>>(node_feat, table, feat, st0);
  feat_tr_kernel<<<nB * 4, 256, 0, stream>>>(feat, featT);
  // laplacian
  dist2_kernel<<<nB * 64, 256, 0, stream>>>(feat, featT, G, part);
  sigred_kernel<<<nB, 64, 0, stream>>>(part, sigma2);
  arow_kernel<<<nB * nN, 256, 0, stream>>>(Lfull, sigma2, G, Dv);
  lkscale_tr_kernel<<<nB * 16, 256, 0, stream>>>(G, Dv, GT);
  // lanczos (half-row per thread, register-resident, no spill)
  lanczos_kernel<<<nB, 512, 0, stream>>>(GT, Q, T);

  const float *stateIn = st0;
  float *stOut[2] = {st1, st2};
  int Din = 64;
  for (int tt = 0; tt < 2; tt++) {
    int C = 10 * Din;
    spect_power_kernel<<<nB, 64, 0, stream>>>(T, Tpow, tt + 1);
    eig1_kernel<<<3 * nB * 4, 256, 0, stream>>>(Tpow, eig_w1, eig_b1, h);
    eig2_kernel<<<3 * nB, 256, 0, stream>>>(h, eig_w2, eig_b2, DD);
    qtstate_kernel<<<nB * nK, Din, 0, stream>>>(Q, stateIn, E);
    ddE_kernel<<<3 * nB * nK, Din, 0, stream>>>(DD, E, F);
    // short diffusion chain -> parts 0..2
    lk_matvec_kernel<<<nB * nN / 8, Din, 0, stream>>>(G, stateIn, Din, msg + 0 * Din, C);
    lk_matvec_kernel<<<nB * nN / 8, Din, 0, stream>>>(G, msg + 0 * Din, C, msg + 1 * Din, C);
    lk_matvec_kernel<<<nB * nN / 8, Din, 0, stream>>>(G, msg + 1 * Din, C, msg + 2 * Din, C);
    // long spectral -> parts 3..5
    longmsg_kernel<<<nB * nN, Din, 0, stream>>>(Q, F, msg, C);
    // edge types -> parts 6..9
    edgemsg_kernel<<<nB * nN / 4, Din, 0, stream>>>(Lfull, stateIn, msg, C);
    // filter layer
    filt_kernel<<<nB * nN / 16, 256, 0, stream>>>(
        msg, tt ? filt_w1 : filt_w0, tt ? filt_b1 : filt_b0, stOut[tt], C);
    stateIn = stOut[tt];
    Din = 128;
  }
  score_kernel<<<nB, 256, 0, stream>>>(st2, filt_wo, filt_bo, att_w, att_b,
                                       (float *)d_out);
}

// Round 7
// 865.607 us; speedup vs baseline: 1.1768x; 1.0091x over previous
//
#include <hip/hip_runtime.h>

// ---------------------------------------------------------------------------
// AdaLanczosNet forward, faithful f32 re-implementation of the JAX reference.
// B=16, N=256, NUM_ATOM=64, K=20, HIDDEN=(128,128), SCALES=10.
// Round 7: spill-free lanczos. Matrix STREAMED from L2 each iteration
// (coalesced, no per-thread residency -> nothing to spill); alpha/qnorm
// reductions fused into the matvec window; 7 barriers/iter (was 11);
// Qb padded stride 257. feat_state+feat_tr fused.
// ---------------------------------------------------------------------------

constexpr int nB = 16;
constexpr int nN = 256;
constexpr int nK = 20;
constexpr int QS = nN + 1;  // padded Qb row stride (bank-conflict-free)
constexpr float EPSF = 1.1920928955078125e-07f;  // np.finfo(float32).eps
constexpr float LBF  = 1e-4f;                    // lanczos breakdown tol

#define DEV static __device__ __forceinline__

// ---------------- Threefry-2x32 (20 rounds) --------------------------------
DEV void tf2x32(unsigned k0, unsigned k1, unsigned x0, unsigned x1,
                unsigned &o0, unsigned &o1) {
  unsigned ks2 = k0 ^ k1 ^ 0x1BD11BDAu;
#define RND(r) { x0 += x1; x1 = (x1 << r) | (x1 >> (32 - r)); x1 ^= x0; }
  x0 += k0;  x1 += k1;
  RND(13) RND(15) RND(26) RND(6)
  x0 += k1;  x1 += ks2 + 1u;
  RND(17) RND(29) RND(16) RND(24)
  x0 += ks2; x1 += k0 + 2u;
  RND(13) RND(15) RND(26) RND(6)
  x0 += k0;  x1 += k1 + 3u;
  RND(17) RND(29) RND(16) RND(24)
  x0 += k1;  x1 += ks2 + 4u;
  RND(13) RND(15) RND(26) RND(6)
  x0 += ks2; x1 += k0 + 5u;
#undef RND
  o0 = x0; o1 = x1;
}

// XLA ErfInv (f32, Giles polynomial, w = -log1p(-x^2))
DEV float erfinv_f32(float x) {
  float w = -log1pf(-x * x);
  float p;
  if (w < 5.0f) {
    w -= 2.5f;
    p = 2.81022636e-08f;
    p = fmaf(p, w, 3.43273939e-07f);
    p = fmaf(p, w, -3.5233877e-06f);
    p = fmaf(p, w, -4.39150654e-06f);
    p = fmaf(p, w, 0.00021858087f);
    p = fmaf(p, w, -0.00125372503f);
    p = fmaf(p, w, -0.00417768164f);
    p = fmaf(p, w, 0.246640727f);
    p = fmaf(p, w, 1.50140941f);
  } else {
    w = sqrtf(w) - 3.0f;
    p = -0.000200214257f;
    p = fmaf(p, w, 0.000100950558f);
    p = fmaf(p, w, 0.00134934322f);
    p = fmaf(p, w, -0.00367342844f);
    p = fmaf(p, w, 0.00573950773f);
    p = fmaf(p, w, -0.0076224613f);
    p = fmaf(p, w, 0.00943887047f);
    p = fmaf(p, w, 1.00167406f);
    p = fmaf(p, w, 2.83297682f);
  }
  return p * x;
}

DEV float jax_normal(unsigned k0, unsigned k1, unsigned idx) {
  unsigned o0, o1;
  tf2x32(k0, k1, 0u /*hi*/, idx /*lo*/, o0, o1);
  unsigned bits = o0 ^ o1;
  float u = __uint_as_float((bits >> 9) | 0x3f800000u) - 1.0f;  // [0,1)
  const float lo = -0.99999994f;
  float v = fmaxf(lo, u * 2.0f + lo);
  return 1.41421356237309515f * erfinv_f32(v);
}

// ---------------- reductions ----------------------------------------------
DEV double waveRedD(double v) {
#pragma unroll
  for (int m = 32; m > 0; m >>= 1) v += __shfl_xor(v, m, 64);
  return v;
}
DEV float waveRedF(float v) {
#pragma unroll
  for (int m = 32; m > 0; m >>= 1) v += __shfl_xor(v, m, 64);
  return v;
}
DEV double blockSumD(double v, double *s4) {
  v = waveRedD(v);
  int w = threadIdx.x >> 6;
  __syncthreads();
  if ((threadIdx.x & 63) == 0) s4[w] = v;
  __syncthreads();
  return s4[0] + s4[1] + s4[2] + s4[3];
}
DEV double sum8(const double *r) {
  return ((r[0] + r[1]) + (r[2] + r[3])) + ((r[4] + r[5]) + (r[6] + r[7]));
}

// ---------------- stage 1: embedding table + one-hot state ----------------
__global__ __launch_bounds__(256) void feat_table_kernel(
    const float *__restrict__ w1, const float *__restrict__ b1,
    const float *__restrict__ w2, const float *__restrict__ b2,
    float *__restrict__ table) {
  int a = blockIdx.x, t = threadIdx.x;
  __shared__ float hh[1024];
  __shared__ float part[256];
  for (int k = t; k < 1024; k += 256)
    hh[k] = fmaxf(w1[(size_t)a * 1024 + k] + b1[k], 0.f);
  __syncthreads();
  int d = t & 63, slice = t >> 6;
  float acc = 0.f;
  for (int k = slice * 256; k < slice * 256 + 256; k++)
    acc += hh[k] * w2[(size_t)k * 64 + d];
  part[t] = acc;
  __syncthreads();
  if (t < 64)
    table[(size_t)a * 64 + t] =
        part[t] + part[64 + t] + part[128 + t] + part[192 + t] + b2[t];
}

// fused: feat gather + one-hot state + featT transpose (per 64-node tile)
__global__ __launch_bounds__(256) void feat_state_tr_kernel(
    const int *__restrict__ nf, const float *__restrict__ table,
    float *__restrict__ feat, float *__restrict__ featT,
    float *__restrict__ state0) {
  int g = blockIdx.x;             // nB*4
  int bb = g >> 2, n0 = (g & 3) * 64;
  int t = threadIdx.x;
  int c = t & 63, r4 = t >> 6;
  __shared__ float tl[64][65];
  __shared__ int av[64];
  if (t < 64) av[t] = nf[bb * nN + n0 + t];
  __syncthreads();
  for (int r = r4; r < 64; r += 4) {
    int a = av[r];
    float v = table[(size_t)a * 64 + c];
    tl[r][c] = v;
    feat[((size_t)(bb * nN + n0 + r)) * 64 + c] = v;
    state0[((size_t)(bb * nN + n0 + r)) * 64 + c] = (c == a) ? 1.f : 0.f;
  }
  __syncthreads();
  for (int r = r4; r < 64; r += 4)
    featT[(size_t)bb * 16384 + (size_t)r * nN + n0 + c] = tl[c][r];
}

// ---------------- stage 2: graph laplacian --------------------------------
__global__ __launch_bounds__(256) void dist2_kernel(
    const float *__restrict__ feat, const float *__restrict__ featT,
    float *__restrict__ G, double *__restrict__ part) {
  int g = blockIdx.x;             // nB*64
  int bb = g >> 6, i0 = (g & 63) * 4;
  int t = threadIdx.x;
  __shared__ float fi[4][64];
  __shared__ double s4[4];
  {
    int r = t >> 6, d = t & 63;
    fi[r][d] = feat[((size_t)(bb * nN + i0 + r)) * 64 + d];
  }
  __syncthreads();
  const float *ft = featT + (size_t)bb * 16384 + t;
  float a0 = 0.f, a1 = 0.f, a2 = 0.f, a3 = 0.f;
#pragma unroll 8
  for (int d = 0; d < 64; d++) {
    float x = ft[(size_t)d * nN];
    float d0 = fi[0][d] - x; a0 += d0 * d0;
    float d1 = fi[1][d] - x; a1 += d1 * d1;
    float d2 = fi[2][d] - x; a2 += d2 * d2;
    float d3 = fi[3][d] - x; a3 += d3 * d3;
  }
  size_t base = ((size_t)bb * nN + i0) * nN + t;
  G[base]           = a0;
  G[base + nN]      = a1;
  G[base + 2 * nN]  = a2;
  G[base + 3 * nN]  = a3;
  double tot = blockSumD((double)a0 + (double)a1 + (double)a2 + (double)a3, s4);
  if (t == 0) part[g] = tot;
}

__global__ __launch_bounds__(64) void sigred_kernel(
    const double *__restrict__ part, float *__restrict__ sigma2) {
  int bb = blockIdx.x, t = threadIdx.x;
  double v = part[(size_t)bb * 64 + t];
  v = waveRedD(v);
  if (t == 0) sigma2[bb] = (float)(v / 65536.0);
}

__global__ __launch_bounds__(256) void arow_kernel(
    const float *__restrict__ Lfull, const float *__restrict__ sigma2,
    float *__restrict__ G, float *__restrict__ Dv) {
  int g = blockIdx.x;
  int i = g % nN, bb = g / nN;
  int t = threadIdx.x;
  __shared__ double s4[4];
  float sig = sigma2[bb];
  size_t idx2 = ((size_t)bb * nN + i) * nN + t;
  float a = expf(-G[idx2] / sig) * Lfull[idx2 * 4];  // adj mask = L[...,0]
  G[idx2] = a;
  double rs = blockSumD((double)a, s4);
  if (t == 0) {
    float r = (float)rs;
    float pad = (r == 0.f) ? 1.f : 0.f;
    Dv[(size_t)bb * nN + i] = 1.f / sqrtf(r + pad);
  }
}

// scale G in place AND write GT = Lk^T (tiled transpose)
__global__ __launch_bounds__(256) void lkscale_tr_kernel(
    float *__restrict__ G, const float *__restrict__ Dv,
    float *__restrict__ GT) {
  int g = blockIdx.x;                 // nB*16
  int bb = g >> 4, tile = g & 15;
  int ti = (tile >> 2) * 64, tj = (tile & 3) * 64;
  int t = threadIdx.x;
  int lj = t & 63, li0 = t >> 6;
  __shared__ float tl[64][65];
  for (int r = li0; r < 64; r += 4) {
    int i = ti + r;
    size_t idx = ((size_t)bb * nN + i) * nN + tj + lj;
    float v = Dv[(size_t)bb * nN + i] * G[idx] * Dv[(size_t)bb * nN + tj + lj];
    G[idx] = v;
    tl[r][lj] = v;
  }
  __syncthreads();
  for (int r = li0; r < 64; r += 4) {
    int j = tj + r;
    GT[((size_t)bb * nN + j) * nN + ti + lj] = tl[lj][r];
  }
}

// ---------------- stage 3: Lanczos (512 threads, streamed matvec) ---------
// Thread u=(h,t): accumulates half-row dot for row t from L2 each iteration
// (coalesced GT columns; block's 256 KB slice is L2-resident). No per-thread
// matrix array -> nothing to spill. alpha & ||qc||^2 partials fused into the
// matvec reduce window; 7 barriers/iter.
__global__ __launch_bounds__(512)
void lanczos_kernel(const float *__restrict__ GT, float *__restrict__ Qout,
                    float *__restrict__ Tout) {
  __shared__ float Qb[nK * QS];          // padded stride 257
  __shared__ float qc[nN], qp[nN], zz[nN];
  __shared__ double zp[2][nN];
  __shared__ float qn2[nK], sAl[nK], sBe[nK], sVa[nK], coef[nK];
  __shared__ double redA[8], redB[8];
  int bb = blockIdx.x, u = threadIdx.x;
  int t = u & 255, h = u >> 8;
  int wv = u >> 6, lane = u & 63;
  int gid = u >> 4, gl = u & 15;

  const float *Gcol = GT + (size_t)bb * (nN * nN) + (size_t)(h * 128) * nN + t;

  // q0 = normal(fold_in(key(42),0), (B,N)); q0 /= ||q0||
  unsigned k0, k1;
  tf2x32(0u, 42u, 0u, 0u, k0, k1);
  float val = 0.f;
  if (h == 0) val = jax_normal(k0, k1, (unsigned)(bb * nN + t));
  {
    double v = waveRedD((double)val * (double)val);
    __syncthreads();
    if (lane == 0) redA[wv] = v;
    __syncthreads();
    double n2 = sum8(redA);
    if (h == 0) {
      qc[t] = val / sqrtf((float)n2);
      qp[t] = 0.f;
    }
  }
  __syncthreads();

  float beta_prev = 0.f, validf = 1.f;

  for (int i = 0; i < nK; i++) {
    // --- P1: matvec half-partials (L2 stream) + fused alpha/q2 partials
    double a0 = 0, a1 = 0, a2 = 0, a3 = 0, a4 = 0, a5 = 0, a6 = 0, a7 = 0;
    {
      const float *qv = qc + h * 128;
#pragma unroll
      for (int jj = 0; jj < 128; jj += 8) {
        a0 += (double)Gcol[(size_t)(jj + 0) * nN] * (double)qv[jj + 0];
        a1 += (double)Gcol[(size_t)(jj + 1) * nN] * (double)qv[jj + 1];
        a2 += (double)Gcol[(size_t)(jj + 2) * nN] * (double)qv[jj + 2];
        a3 += (double)Gcol[(size_t)(jj + 3) * nN] * (double)qv[jj + 3];
        a4 += (double)Gcol[(size_t)(jj + 4) * nN] * (double)qv[jj + 4];
        a5 += (double)Gcol[(size_t)(jj + 5) * nN] * (double)qv[jj + 5];
        a6 += (double)Gcol[(size_t)(jj + 6) * nN] * (double)qv[jj + 6];
        a7 += (double)Gcol[(size_t)(jj + 7) * nN] * (double)qv[jj + 7];
      }
    }
    double part = ((a0 + a1) + (a2 + a3)) + ((a4 + a5) + (a6 + a7));
    zp[h][t] = part;
    double apart = (double)qc[t] * part;
    double qpart = (h == 0) ? (double)qc[t] * (double)qc[t] : 0.0;
    apart = waveRedD(apart);
    qpart = waveRedD(qpart);
    if (lane == 0) { redA[wv] = apart; redB[wv] = qpart; }
    __syncthreads();                                   // B1
    // --- P2: alpha; z assembly (h==0) | Qb column-i store (h==1)
    float alpha = (float)sum8(redA);
    if (h == 0) {
      float zi = (float)(zp[0][t] + zp[1][t]);
      zi = zi - alpha * qc[t] - beta_prev * qp[t];
      zz[t] = zi;
    } else {
      Qb[i * QS + t] = qc[t];
      if (t == 0) qn2[i] = (float)sum8(redB);
    }
    __syncthreads();                                   // B2
    // --- P3: reorth pass-1 coefficients (16-lane group per k, all parallel)
    if (gid < i) {
      double p = 0.0;
#pragma unroll
      for (int j = 0; j < 16; j++) {
        int n0 = gl + 16 * j;
        p += (double)Qb[gid * QS + n0] * (double)zz[n0];
      }
#pragma unroll
      for (int m = 1; m <= 8; m <<= 1) p += __shfl_xor(p, m, 64);
      if (gl == 0)
        coef[gid] = (float)(p / ((double)qn2[gid] + (double)EPSF));
    }
    __syncthreads();                                   // B3
    // --- P4: subtract pass-1
    if (h == 0) {
      double sub = 0.0;
      for (int k = 0; k < i; k++)
        sub += (double)Qb[k * QS + t] * (double)coef[k];
      zz[t] = (float)((double)zz[t] - sub);
    }
    __syncthreads();                                   // B4
    // --- P5: reorth pass-2 coefficients
    if (gid < i) {
      double p = 0.0;
#pragma unroll
      for (int j = 0; j < 16; j++) {
        int n0 = gl + 16 * j;
        p += (double)Qb[gid * QS + n0] * (double)zz[n0];
      }
#pragma unroll
      for (int m = 1; m <= 8; m <<= 1) p += __shfl_xor(p, m, 64);
      if (gl == 0)
        coef[gid] = (float)(p / ((double)qn2[gid] + (double)EPSF));
    }
    __syncthreads();                                   // B5
    // --- P6: subtract pass-2 + beta partial
    double bpart = 0.0;
    if (h == 0) {
      double sub = 0.0;
      for (int k = 0; k < i; k++)
        sub += (double)Qb[k * QS + t] * (double)coef[k];
      float znew = (float)((double)zz[t] - sub);
      zz[t] = znew;
      bpart = (double)znew * (double)znew;
    }
    bpart = waveRedD(bpart);
    if (lane == 0) redA[wv] = bpart;
    __syncthreads();                                   // B6
    // --- P7: beta, validity, q update
    float beta = sqrtf((float)sum8(redA));
    validf *= (beta >= LBF) ? 1.f : 0.f;
    if (u == 0) {
      sAl[i] = alpha;
      sBe[i] = beta;
      sVa[i] = validf;
    }
    if (h == 0) {
      float qnext = zz[t] * validf / (beta + EPSF);
      qp[t] = qc[t];
      qc[t] = qnext;
    }
    __syncthreads();                                   // B7
    beta_prev = beta;
  }

  // idx = sum(valid); mask Q rows/cols; build T
  float idxf = 0.f;
  for (int k = 0; k < nK; k++) idxf += sVa[k];
  int idx = (int)idxf;
  if (h == 0) {
    float rowok = ((t < idx) || (idx >= nN)) ? 1.f : 0.f;
    for (int k = 0; k < nK; k++)
      Qout[((size_t)bb * nN + t) * nK + k] = Qb[k * QS + t] * sVa[k] * rowok;
  }
  for (int e = u; e < nK * nK; e += 512) {
    int i = e / nK, j = e % nK;
    float v = 0.f;
    if (i == j) v = sAl[i] * sVa[i];
    else if (j == i + 1) v = sBe[i] * sVa[i];
    else if (i == j + 1) v = sBe[j] * sVa[j];
    Tout[(size_t)bb * nK * nK + e] = v;
  }
}

// ---------------- stage 4: gated T powers (per batch) ----------------------
__global__ __launch_bounds__(64) void spect_power_kernel(
    const float *__restrict__ Tin, float *__restrict__ Tpow, int fold_data) {
  __shared__ float T_[nK * nK], TT[nK * nK], TTn[nK * nK];
  __shared__ float Tb[nK], Tbn[nK];
  int bb = blockIdx.x, t = threadIdx.x;
  for (int e = t; e < nK * nK; e += 64) {
    float v = Tin[(size_t)bb * nK * nK + e];
    T_[e] = v;
    TT[e] = v;
  }
  unsigned k0, k1;
  tf2x32(0u, 42u, 0u, (unsigned)fold_data, k0, k1);
  if (t < nK) Tb[t] = jax_normal(k0, k1, (unsigned)(bb * nK + t));
  __syncthreads();
  float pv = (t < nK) ? Tb[t] * Tb[t] : 0.f;
  float nb = sqrtf(waveRedF(pv));
  if (t < nK) Tb[t] = Tb[t] / nb;
  __syncthreads();
  for (int ii = 0; ii < 8; ii++) {
    if (ii == 3 || ii == 5 || ii == 7) {
      int s = (ii - 3) / 2;
      for (int e = t; e < nK * nK; e += 64)
        Tpow[((size_t)s * nB + bb) * nK * nK + e] = TT[e];
    }
    __syncthreads();
    for (int e = t; e < nK * nK; e += 64) {
      int i = e / nK, j = e % nK;
      float a = 0.f;
      for (int l = 0; l < nK; l++) a += TT[i * nK + l] * T_[l * nK + j];
      TTn[e] = a;
    }
    if (t < nK) {
      float a = 0.f;
      for (int l = 0; l < nK; l++) a += T_[t * nK + l] * Tb[l];
      Tbn[t] = a;
    }
    __syncthreads();
    float pn = (t < nK) ? Tbn[t] * Tb[t] : 0.f;
    float pd = (t < nK) ? Tb[t] * Tb[t] : 0.f;
    float num = waveRedF(pn);
    float den = waveRedF(pd);
    float lmax = num / (den + EPSF);
    float keep = (fabsf(lmax) <= 1.0f) ? 1.f : 0.f;
    __syncthreads();
    for (int e = t; e < nK * nK; e += 64) TT[e] = TTn[e] * keep;
    float p2 = (t < nK) ? Tbn[t] * Tbn[t] : 0.f;
    float nn = sqrtf(waveRedF(p2));
    if (t < nK) Tb[t] = Tbn[t] / (nn + EPSF);
    __syncthreads();
  }
}

// ---------------- stage 4b: eigen maps ------------------------------------
__global__ __launch_bounds__(256) void eig1_kernel(
    const float *__restrict__ Tpow, const float *__restrict__ w1p,
    const float *__restrict__ b1p, float *__restrict__ h) {
  int g = blockIdx.x;                 // 3*B*4 blocks
  int chunk = g & 3, bb = (g >> 2) % nB, s = g / (4 * nB);
  int t = threadIdx.x;
  __shared__ float tp[nK * nK];
  for (int e = t; e < nK * nK; e += 256)
    tp[e] = Tpow[((size_t)s * nB + bb) * nK * nK + e];
  __syncthreads();
  int o = chunk * 256 + t;
  const float *W = w1p + (size_t)s * 400 * 1024;
  float acc = b1p[(size_t)s * 1024 + o];
  for (int k = 0; k < 400; k++) acc += tp[k] * W[(size_t)k * 1024 + o];
  h[((size_t)s * nB + bb) * 1024 + o] = fmaxf(acc, 0.f);
}

__global__ __launch_bounds__(256) void eig2_kernel(
    const float *__restrict__ h, const float *__restrict__ w2p,
    const float *__restrict__ b2p, float *__restrict__ DD) {
  int g = blockIdx.x;  // 3*B blocks
  int bb = g % nB, s = g / nB;
  int t = threadIdx.x;
  __shared__ float hh[1024];
  __shared__ float raw[nK * nK];
  for (int e = t; e < 1024; e += 256)
    hh[e] = h[((size_t)s * nB + bb) * 1024 + e];
  __syncthreads();
  const float *W = w2p + (size_t)s * 1024 * 400;
  for (int kl = t; kl < 400; kl += 256) {
    float acc = b2p[(size_t)s * 400 + kl];
    for (int o = 0; o < 1024; o++) acc += hh[o] * W[(size_t)o * 400 + kl];
    raw[kl] = acc;
  }
  __syncthreads();
  for (int e = t; e < 400; e += 256) {
    int i = e / nK, j = e % nK;
    int mi = i < j ? i : j, ma = i < j ? j : i;
    DD[((size_t)s * nB + bb) * 400 + e] = raw[mi * nK + ma];
  }
}

// ---------------- stage 5: message assembly -------------------------------
__global__ void qtstate_kernel(const float *__restrict__ Q,
                               const float *__restrict__ state,
                               float *__restrict__ E) {
  int g = blockIdx.x;
  int k = g % nK, bb = g / nK;
  int t = threadIdx.x, Din = blockDim.x;
  __shared__ float qcol[nN];
  for (int n = t; n < nN; n += Din) qcol[n] = Q[((size_t)bb * nN + n) * nK + k];
  __syncthreads();
  const float *st = state + (size_t)bb * nN * Din;
  float acc = 0.f;
  for (int n = 0; n < nN; n++) acc += qcol[n] * st[(size_t)n * Din + t];
  E[((size_t)bb * nK + k) * Din + t] = acc;
}

__global__ void ddE_kernel(const float *__restrict__ DD,
                           const float *__restrict__ E,
                           float *__restrict__ F) {
  int g = blockIdx.x;
  int k = g % nK, bb = (g / nK) % nB, s = g / (nK * nB);
  int t = threadIdx.x, Din = blockDim.x;
  __shared__ float dr[nK];
  if (t < nK) dr[t] = DD[((size_t)s * nB + bb) * 400 + k * nK + t];
  __syncthreads();
  float acc = 0.f;
  for (int l = 0; l < nK; l++)
    acc += dr[l] * E[((size_t)bb * nK + l) * Din + t];
  F[(((size_t)s * nB + bb) * nK + k) * Din + t] = acc;
}

// out = Lk @ in, 8 rows per block (rows staged in LDS, input reused 8x)
__global__ void lk_matvec_kernel(const float *__restrict__ Lk,
                                 const float *__restrict__ in, int inStride,
                                 float *__restrict__ out, int outStride) {
  int g = blockIdx.x;                 // nB*nN/8
  int bb = g >> 5, r0 = (g & 31) * 8;
  int t = threadIdx.x, Din = blockDim.x;
  __shared__ float rows[8][nN];
  for (int e = t; e < 8 * nN; e += Din) {
    int r = e >> 8, j = e & 255;
    rows[r][j] = Lk[((size_t)bb * nN + r0 + r) * nN + j];
  }
  __syncthreads();
  float acc[8] = {0.f, 0.f, 0.f, 0.f, 0.f, 0.f, 0.f, 0.f};
  const float *ip = in + (size_t)bb * nN * inStride + t;
  for (int j = 0; j < nN; j++) {
    float x = ip[(size_t)j * inStride];
#pragma unroll
    for (int r = 0; r < 8; r++) acc[r] += rows[r][j] * x;
  }
#pragma unroll
  for (int r = 0; r < 8; r++)
    out[((size_t)bb * nN + r0 + r) * outStride + t] = acc[r];
}

// msg parts 3..5: Q @ F[s]
__global__ void longmsg_kernel(const float *__restrict__ Q,
                               const float *__restrict__ F,
                               float *__restrict__ msg, int C) {
  int g = blockIdx.x;
  int i = g % nN, bb = g / nN;
  int t = threadIdx.x, Din = blockDim.x;
  __shared__ float qr[nK];
  if (t < nK) qr[t] = Q[((size_t)bb * nN + i) * nK + t];
  __syncthreads();
  for (int s = 0; s < 3; s++) {
    float acc = 0.f;
    for (int k = 0; k < nK; k++)
      acc += qr[k] * F[(((size_t)s * nB + bb) * nK + k) * Din + t];
    msg[((size_t)bb * nN + i) * C + (3 + s) * Din + t] = acc;
  }
}

// msg parts 6..9: L[...,e] @ state, 4 rows/block, float4 over the 4 edgetypes
__global__ void edgemsg_kernel(const float *__restrict__ Lfull,
                               const float *__restrict__ state,
                               float *__restrict__ msg, int C) {
  int g = blockIdx.x;                 // nB*nN/4
  int bb = g >> 6, r0 = (g & 63) * 4;
  int t = threadIdx.x, Din = blockDim.x;
  __shared__ float4 rows4[4][nN];     // 16 KiB
  const float4 *L4 = (const float4 *)Lfull;
  for (int e = t; e < 4 * nN; e += Din) {
    int r = e >> 8, j = e & 255;
    rows4[r][j] = L4[((size_t)bb * nN + r0 + r) * nN + j];
  }
  __syncthreads();
  float acc[4][4];
#pragma unroll
  for (int r = 0; r < 4; r++)
#pragma unroll
    for (int e = 0; e < 4; e++) acc[r][e] = 0.f;
  const float *st = state + (size_t)bb * nN * Din + t;
  for (int j = 0; j < nN; j++) {
    float x = st[(size_t)j * Din];
#pragma unroll
    for (int r = 0; r < 4; r++) {
      float4 lv = rows4[r][j];
      acc[r][0] += lv.x * x;
      acc[r][1] += lv.y * x;
      acc[r][2] += lv.z * x;
      acc[r][3] += lv.w * x;
    }
  }
#pragma unroll
  for (int r = 0; r < 4; r++)
#pragma unroll
    for (int e = 0; e < 4; e++)
      msg[((size_t)bb * nN + r0 + r) * C + (6 + e) * Din + t] = acc[r][e];
}

// state_next = relu(msg @ W + b); 16 rows per block to amortize W reads
__global__ __launch_bounds__(256) void filt_kernel(
    const float *__restrict__ msg, const float *__restrict__ W,
    const float *__restrict__ bias, float *__restrict__ out, int C) {
  int g = blockIdx.x;                 // (B*N)/16
  int base = g * 16;
  int t = threadIdx.x;
  int o = t & 127, ih = t >> 7;       // ih: 0/1 -> rows 0..7 / 8..15
  __shared__ float mt[16][64];
  float acc[8];
  float bo = bias[o];
#pragma unroll
  for (int r = 0; r < 8; r++) acc[r] = bo;
  for (int c0 = 0; c0 < C; c0 += 64) {
    __syncthreads();
    for (int e = t; e < 16 * 64; e += 256) {
      int r = e >> 6, c = e & 63;
      mt[r][c] = msg[((size_t)(base + r)) * C + c0 + c];
    }
    __syncthreads();
    for (int c = 0; c < 64; c++) {
      float w = W[(size_t)(c0 + c) * 128 + o];
#pragma unroll
      for (int r = 0; r < 8; r++) acc[r] += mt[ih * 8 + r][c] * w;
    }
  }
#pragma unroll
  for (int r = 0; r < 8; r++)
    out[((size_t)(base + ih * 8 + r)) * 128 + o] = fmaxf(acc[r], 0.f);
}

// ---------------- stage 6: readout ----------------------------------------
__global__ __launch_bounds__(256) void score_kernel(
    const float *__restrict__ state, const float *__restrict__ wo,
    const float *__restrict__ bo, const float *__restrict__ aw,
    const float *__restrict__ ab, float *__restrict__ out) {
  __shared__ double s4[4];
  int bb = blockIdx.x, t = threadIdx.x;
  const float *st = state + ((size_t)bb * nN + t) * 128;
  float sy = bo[0], sa = ab[0];
  for (int o = 0; o < 128; o++) {
    float v = st[o];
    sy += v * wo[o];
    sa += v * aw[o];
  }
  float att = 1.f / (1.f + expf(-sa));
  double m = blockSumD((double)(att * sy), s4);
  if (t == 0) out[bb] = (float)(m / (double)nN);
}

// ---------------------------------------------------------------------------
extern "C" void kernel_launch(void *const *d_in, const int *in_sizes, int n_in,
                              void *d_out, int out_size, void *d_ws,
                              size_t ws_size, hipStream_t stream) {
  (void)in_sizes; (void)n_in; (void)out_size;
  const int   *node_feat = (const int *)d_in[0];
  const float *Lfull     = (const float *)d_in[1];
  const float *emb_w1    = (const float *)d_in[2];
  const float *emb_b1    = (const float *)d_in[3];
  const float *emb_w2    = (const float *)d_in[4];
  const float *emb_b2    = (const float *)d_in[5];
  const float *eig_w1    = (const float *)d_in[6];
  const float *eig_b1    = (const float *)d_in[7];
  const float *eig_w2    = (const float *)d_in[8];
  const float *eig_b2    = (const float *)d_in[9];
  const float *filt_w0   = (const float *)d_in[10];
  const float *filt_b0   = (const float *)d_in[11];
  const float *filt_w1   = (const float *)d_in[12];
  const float *filt_b1   = (const float *)d_in[13];
  const float *filt_wo   = (const float *)d_in[14];
  const float *filt_bo   = (const float *)d_in[15];
  const float *att_w     = (const float *)d_in[16];
  const float *att_b     = (const float *)d_in[17];

  // workspace layout (floats)
  float *ws   = (float *)d_ws;
  float *G    = ws;                    // B*N*N           = 1048576
  float *msg  = G + 1048576;           // B*N*1280        = 5242880
  float *st0  = msg + 5242880;         // B*N*64
  float *st1  = st0 + 262144;          // B*N*128
  float *st2  = st1 + 524288;          // B*N*128
  float *feat = st2 + 524288;          // B*N*64
  float *table= feat + 262144;         // 64*64
  float *Q    = table + 4096;          // B*N*K
  float *T    = Q + 81920;             // B*K*K
  float *Tpow = T + 6400;              // 3*B*K*K
  float *DD   = Tpow + 19200;          // 3*B*K*K
  float *h    = DD + 19200;            // 3*B*1024
  float *E    = h + 49152;             // B*K*128
  float *F    = E + 40960;             // 3*B*K*128
  float *Dv   = F + 122880;            // B*N
  double *part   = (double *)(Dv + 4096);   // B*N doubles (8-byte aligned)
  float  *sigma2 = (float *)(part + nB * nN);
  // GT and featT alias the msg region (both dead before msg is written)
  float *GT    = msg;                  // B*N*N = 1048576 floats
  float *featT = msg + 1048576;        // B*64*256 = 262144 floats
  const size_t needBytes = (size_t)(8220432) * 4;
  if (ws_size < needBytes) return;

  // embedding + one-hot state + featT (fused)
  feat_table_kernel<<<64, 256, 0, stream>>>(emb_w1, emb_b1, emb_w2, emb_b2, table);
  feat_state_tr_kernel<<<nB * 4, 256, 0, stream>>>(node_feat, table, feat,
                                                   featT, st0);
  // laplacian
  dist2_kernel<<<nB * 64, 256, 0, stream>>>(feat, featT, G, part);
  sigred_kernel<<<nB, 64, 0, stream>>>(part, sigma2);
  arow_kernel<<<nB * nN, 256, 0, stream>>>(Lfull, sigma2, G, Dv);
  lkscale_tr_kernel<<<nB * 16, 256, 0, stream>>>(G, Dv, GT);
  // lanczos (streamed matvec, spill-free)
  lanczos_kernel<<<nB, 512, 0, stream>>>(GT, Q, T);

  const float *stateIn = st0;
  float *stOut[2] = {st1, st2};
  int Din = 64;
  for (int tt = 0; tt < 2; tt++) {
    int C = 10 * Din;
    spect_power_kernel<<<nB, 64, 0, stream>>>(T, Tpow, tt + 1);
    eig1_kernel<<<3 * nB * 4, 256, 0, stream>>>(Tpow, eig_w1, eig_b1, h);
    eig2_kernel<<<3 * nB, 256, 0, stream>>>(h, eig_w2, eig_b2, DD);
    qtstate_kernel<<<nB * nK, Din, 0, stream>>>(Q, stateIn, E);
    ddE_kernel<<<3 * nB * nK, Din, 0, stream>>>(DD, E, F);
    // short diffusion chain -> parts 0..2
    lk_matvec_kernel<<<nB * nN / 8, Din, 0, stream>>>(G, stateIn, Din, msg + 0 * Din, C);
    lk_matvec_kernel<<<nB * nN / 8, Din, 0, stream>>>(G, msg + 0 * Din, C, msg + 1 * Din, C);
    lk_matvec_kernel<<<nB * nN / 8, Din, 0, stream>>>(G, msg + 1 * Din, C, msg + 2 * Din, C);
    // long spectral -> parts 3..5
    longmsg_kernel<<<nB * nN, Din, 0, stream>>>(Q, F, msg, C);
    // edge types -> parts 6..9
    edgemsg_kernel<<<nB * nN / 4, Din, 0, stream>>>(Lfull, stateIn, msg, C);
    // filter layer
    filt_kernel<<<nB * nN / 16, 256, 0, stream>>>(
        msg, tt ? filt_w1 : filt_w0, tt ? filt_b1 : filt_b0, stOut[tt], C);
    stateIn = stOut[tt];
    Din = 128;
  }
  score_kernel<<<nB, 256, 0, stream>>>(st2, filt_wo, filt_bo, att_w, att_b,
                                       (float *)d_out);
}